// Round 6
// baseline (2137.179 us; speedup 1.0000x reference)
//
#include <hip/hip_runtime.h>
#include <hip/hip_bf16.h>

#define NN 100000
#define NE 100000
#define NCNT (14 * NN)
#define LP 136    // padded LDS pitch (bf16) for encoder kernels
#define LP2 168   // pitch for K=160 (meta)
#define SCAN_CHUNK 4096
#define NSCB ((NCNT + SCAN_CHUNK - 1) / SCAN_CHUNK)

typedef __bf16 bf16;
typedef __bf16 bf16x8 __attribute__((ext_vector_type(8)));
typedef float  f32x4  __attribute__((ext_vector_type(4)));
typedef unsigned long long u64;

// ---------- generic helpers ----------

__device__ __forceinline__ void gl2lds16(const bf16* g, bf16* l) {
    __builtin_amdgcn_global_load_lds(
        (const __attribute__((address_space(1))) void*)g,
        (__attribute__((address_space(3))) void*)l, 16, 0, 0);
}

__device__ __forceinline__ void zacc8(f32x4 acc[8]) {
    f32x4 z = {0.f, 0.f, 0.f, 0.f};
#pragma unroll
    for (int n = 0; n < 8; ++n) acc[n] = z;
}

// per-wave GroupNorm(1) stats: wave holds 16 full rows; rows (lane>>4)*4+r
__device__ __forceinline__ void gnstats(const f32x4 acc[8], float mean[4], float rs[4]) {
    float s1[4], s2[4];
#pragma unroll
    for (int r = 0; r < 4; ++r) { s1[r] = 0.f; s2[r] = 0.f; }
#pragma unroll
    for (int n = 0; n < 8; ++n)
#pragma unroll
        for (int r = 0; r < 4; ++r) { float v = acc[n][r]; s1[r] += v; s2[r] += v * v; }
#pragma unroll
    for (int off = 1; off < 16; off <<= 1) {
#pragma unroll
        for (int r = 0; r < 4; ++r) {
            s1[r] += __shfl_xor(s1[r], off, 64);
            s2[r] += __shfl_xor(s2[r], off, 64);
        }
    }
#pragma unroll
    for (int r = 0; r < 4; ++r) {
        const float m = s1[r] * 0.0078125f;
        const float v = fmaxf(s2[r] * 0.0078125f - m * m, 0.f);
        mean[r] = m;
        rs[r] = rsqrtf(v + 1e-5f);
    }
}

// ---------- encoder-path helpers ----------

template<int PITCH, int COLS>
__device__ inline void stageWB(const bf16* __restrict__ Wg, bf16* Wl) {
    constexpr int NV = 128 * COLS / 8;
    for (int i = threadIdx.x; i < NV; i += 256) {
        const int e = i * 8;
        const int r = e / COLS, c = e % COLS;
        *(float4*)(&Wl[r * PITCH + c]) = ((const float4*)Wg)[i];
    }
}

template<int PITCH, int KSTEPS>
__device__ inline void mmaT(const bf16* Al, const bf16* Wl, int m0, int lane, f32x4 acc[8]) {
#pragma unroll
    for (int kk = 0; kk < KSTEPS; ++kk) {
        bf16x8 a = *(const bf16x8*)(&Al[(m0 + (lane & 15)) * PITCH + kk * 32 + (lane >> 4) * 8]);
#pragma unroll
        for (int n = 0; n < 8; ++n) {
            bf16x8 b = *(const bf16x8*)(&Wl[(n * 16 + (lane & 15)) * PITCH + kk * 32 + (lane >> 4) * 8]);
            acc[n] = __builtin_amdgcn_mfma_f32_16x16x32_bf16(a, b, acc[n], 0, 0, 0);
        }
    }
}

// ---------- k_round helpers (8-wave block, M=128) ----------

// stage one 128x128 bf16 W into WLbase (rows of 256B, slot ^= (row&7) via pre-swizzled src)
// 8 waves x 4 instrs x 1KB = 32KB
__device__ __forceinline__ void stageW(const bf16* __restrict__ Wg, bf16* WLbase,
                                       int w, int lane) {
#pragma unroll
    for (int k = 0; k < 4; ++k) {
        const int R = (w * 4 + k) * 4 + (lane >> 4);
        const int sg = (lane & 15) ^ ((k & 1) * 4 + (lane >> 4));   // == (lane&15) ^ (R&7)
        gl2lds16(Wg + R * 128 + sg * 8, WLbase + (w * 4 + k) * 512);
    }
}

// B-frag reads from swizzled W tile + MFMA
__device__ __forceinline__ void mmaW(const bf16* B, const bf16x8 afr[4],
                                     int r, int h, int r7, f32x4 acc[8]) {
#pragma unroll
    for (int kk = 0; kk < 4; ++kk) {
        const int sl = ((kk * 4 + h) ^ r7) * 8;
#pragma unroll
        for (int n = 0; n < 8; ++n) {
            const bf16x8 b = *(const bf16x8*)(B + (n * 16 + r) * 128 + sl);
            acc[n] = __builtin_amdgcn_mfma_f32_16x16x32_bf16(afr[kk], b, acc[n], 0, 0, 0);
        }
    }
}

__device__ __forceinline__ void loadrow(bf16x8 e[4], const bf16* __restrict__ feat,
                                        int s, int h) {
    const bf16x8* q = (const bf16x8*)(feat + (size_t)s * 128 + h * 8);
    e[0] = q[0]; e[1] = q[4]; e[2] = q[8]; e[3] = q[12];
}

__device__ __forceinline__ void faccum(float ag[4][8], const bf16x8 e[4]) {
#pragma unroll
    for (int kk = 0; kk < 4; ++kk)
#pragma unroll
        for (int j = 0; j < 8; ++j) ag[kk][j] += (float)e[kk][j];
}

// ---------- weight conversion + nodes output slice (one kernel) ----------

__global__ __launch_bounds__(256) void k_cvt_all(
    const float* __restrict__ in2W, const float* __restrict__ seg2W,
    const float* __restrict__ metaW, const float* __restrict__ ctrW,
    const float* __restrict__ ctr2W, const float* __restrict__ edgeW,
    bf16* __restrict__ wIn2, bf16* __restrict__ wSeg2, bf16* __restrict__ wMeta,
    bf16* __restrict__ wCtr, bf16* __restrict__ wCtr2, bf16* __restrict__ wEdge,
    const float* __restrict__ nodes, float* __restrict__ outp)
{
    for (int j = blockIdx.x * 256 + threadIdx.x; j < 2 * NN; j += gridDim.x * 256)
        outp[(size_t)NN * 128 + j] = nodes[(size_t)(j >> 1) * 8 + (j & 1)];
    const int total = 16384 + 16384 + 20480 + 65536 + 65536 + 917504;
    for (int i = blockIdx.x * 256 + threadIdx.x; i < total; i += gridDim.x * 256) {
        int j = i;
        if (j < 16384) { wIn2[j] = (bf16)in2W[j]; continue; }
        j -= 16384;
        if (j < 16384) { wSeg2[j] = (bf16)seg2W[j]; continue; }
        j -= 16384;
        if (j < 20480) {
            const int r = j / 160, c = j % 160;
            wMeta[j] = (bf16)(c < 132 ? metaW[r * 132 + c] : 0.f);
            continue;
        }
        j -= 20480;
        if (j < 65536) { wCtr[j] = (bf16)ctrW[j]; continue; }
        j -= 65536;
        if (j < 65536) { wCtr2[j] = (bf16)ctr2W[j]; continue; }
        j -= 65536;
        wEdge[j] = (bf16)edgeW[j];
    }
}

// ---------- CSR build ----------

__global__ __launch_bounds__(256) void k_count(const int* __restrict__ idx,
                                               const int* __restrict__ mask,
                                               int* __restrict__ cnt) {
    __shared__ int lim[14];
    if (threadIdx.x < 14) lim[threadIdx.x] = min(mask[threadIdx.x], NE);
    __syncthreads();
    for (int i = blockIdx.x * 256 + threadIdx.x; i < 14 * NE; i += gridDim.x * 256) {
        const int e = i / 14, t = i - e * 14;
        if (e < lim[t]) atomicAdd(&cnt[t * NN + idx[(size_t)e * 28 + 2 * t]], 1);
    }
}

__global__ __launch_bounds__(256) void k_scanA(const int* __restrict__ cnt,
                                               int* __restrict__ ptr,
                                               int* __restrict__ tot) {
    __shared__ int sm[256];
    const int tid = threadIdx.x;
    const int base = blockIdx.x * SCAN_CHUNK + tid * 16;
    int v[16]; int run = 0;
#pragma unroll
    for (int j = 0; j < 16; ++j) {
        const int x = (base + j < NCNT) ? cnt[base + j] : 0;
        v[j] = run; run += x;
    }
    sm[tid] = run; __syncthreads();
    for (int d = 1; d < 256; d <<= 1) {
        int t = 0;
        if (tid >= d) t = sm[tid - d];
        __syncthreads();
        sm[tid] += t;
        __syncthreads();
    }
    const int off = sm[tid] - run;
#pragma unroll
    for (int j = 0; j < 16; ++j)
        if (base + j < NCNT) ptr[base + j] = v[j] + off;
    if (tid == 255) tot[blockIdx.x] = sm[255];
}

__global__ void k_scanB(int* __restrict__ tot) {
    if (threadIdx.x == 0 && blockIdx.x == 0) {
        int acc = 0;
        for (int b = 0; b < NSCB; ++b) { const int t = tot[b]; tot[b] = acc; acc += t; }
        tot[NSCB] = acc;
    }
}

__global__ __launch_bounds__(256) void k_scanC(int* __restrict__ ptr,
                                               int* __restrict__ cursor,
                                               const int* __restrict__ tot) {
    const int base = blockIdx.x * SCAN_CHUNK;
    const int o = tot[blockIdx.x];
    for (int j = threadIdx.x; j < SCAN_CHUNK; j += 256) {
        const int i = base + j;
        if (i < NCNT) { const int p = ptr[i] + o; ptr[i] = p; cursor[i] = p; }
    }
    if (blockIdx.x == 0 && threadIdx.x == 0) ptr[NCNT] = tot[NSCB];
}

// elist entry: (edge_id << 32) | src  -> sortable by edge id, src in low word
__global__ __launch_bounds__(256) void k_fill(const int* __restrict__ idx,
                                              const int* __restrict__ mask,
                                              int* __restrict__ cursor,
                                              u64* __restrict__ el) {
    __shared__ int lim[14];
    if (threadIdx.x < 14) lim[threadIdx.x] = min(mask[threadIdx.x], NE);
    __syncthreads();
    for (int i = blockIdx.x * 256 + threadIdx.x; i < 14 * NE; i += gridDim.x * 256) {
        const int e = i / 14, t = i - e * 14;
        if (e < lim[t]) {
            const int dst = idx[(size_t)e * 28 + 2 * t];
            const int src = idx[(size_t)e * 28 + 2 * t + 1];
            const int pos = atomicAdd(&cursor[t * NN + dst], 1);
            el[pos] = ((u64)(unsigned)e << 32) | (unsigned)src;
        }
    }
}

__global__ __launch_bounds__(256) void k_sortseg(const int* __restrict__ ptr,
                                                 u64* __restrict__ el) {
    for (int i = blockIdx.x * 256 + threadIdx.x; i < NCNT; i += gridDim.x * 256) {
        const int s = ptr[i], e2 = ptr[i + 1];
        for (int a = s + 1; a < e2; ++a) {
            const u64 key = el[a];
            int b = a - 1;
            while (b >= s && el[b] > key) { el[b + 1] = el[b]; --b; }
            el[b + 1] = key;
        }
    }
}

// ---------- input encoder ----------

__global__ __launch_bounds__(256) void k_in(
    const float* __restrict__ nodes,
    const float* __restrict__ in1W, const float* __restrict__ in1b,
    const bf16* __restrict__ wIn2,
    const float* __restrict__ ing, const float* __restrict__ inbg,
    const float* __restrict__ seg1W, const float* __restrict__ seg1b,
    const bf16* __restrict__ wSeg2,
    const float* __restrict__ segg, const float* __restrict__ segbg,
    bf16* __restrict__ outPre)
{
    __shared__ __align__(16) bf16 Wl[128 * LP];
    __shared__ __align__(16) bf16 Al[64 * LP];
    __shared__ float w0[128], w1[128], bb[128];
    __shared__ float xs[64][4];
    const int tid = threadIdx.x;
    const int row0 = blockIdx.x * 64;
    if (tid < 64) {
        const int row = row0 + tid;
        float4 x = {0.f, 0.f, 0.f, 0.f};
        if (row < NN) x = *(const float4*)(nodes + (size_t)row * 8);
        xs[tid][0] = x.x; xs[tid][1] = x.y; xs[tid][2] = x.z; xs[tid][3] = x.w;
    }
    if (tid < 128) { w0[tid] = in1W[tid * 2]; w1[tid] = in1W[tid * 2 + 1]; bb[tid] = in1b[tid]; }
    stageWB<LP, 128>(wIn2, Wl);
    __syncthreads();
    for (int i = tid; i < 64 * 128; i += 256) {
        const int r = i >> 7, j = i & 127;
        Al[r * LP + j] = (bf16)fmaxf(xs[r][0] * w0[j] + xs[r][1] * w1[j] + bb[j], 0.f);
    }
    __syncthreads();
    const int lane = tid & 63, m0 = (tid >> 6) * 16;
    f32x4 accP[8]; zacc8(accP);
    mmaT<LP, 4>(Al, Wl, m0, lane, accP);
    __syncthreads();
    if (tid < 128) { w0[tid] = seg1W[tid * 2]; w1[tid] = seg1W[tid * 2 + 1]; bb[tid] = seg1b[tid]; }
    stageWB<LP, 128>(wSeg2, Wl);
    __syncthreads();
    for (int i = tid; i < 64 * 128; i += 256) {
        const int r = i >> 7, j = i & 127;
        Al[r * LP + j] = (bf16)fmaxf(xs[r][2] * w0[j] + xs[r][3] * w1[j] + bb[j], 0.f);
    }
    __syncthreads();
    f32x4 accQ[8]; zacc8(accQ);
    mmaT<LP, 4>(Al, Wl, m0, lane, accQ);

    float mP[4], rP[4], mQ[4], rQ[4];
    gnstats(accP, mP, rP);
    gnstats(accQ, mQ, rQ);
    float gP[8], bP[8], gQ[8], bQ[8];
#pragma unroll
    for (int n = 0; n < 8; ++n) {
        const int c = n * 16 + (lane & 15);
        gP[n] = ing[c]; bP[n] = inbg[c]; gQ[n] = segg[c]; bQ[n] = segbg[c];
    }
#pragma unroll
    for (int r = 0; r < 4; ++r) {
        const int row = row0 + m0 + (lane >> 4) * 4 + r;
        if (row < NN) {
#pragma unroll
            for (int n = 0; n < 8; ++n) {
                const float yp = (accP[n][r] - mP[r]) * rP[r] * gP[n] + bP[n];
                const float yq = (accQ[n][r] - mQ[r]) * rQ[r] * gQ[n] + bQ[n];
                outPre[(size_t)row * 128 + n * 16 + (lane & 15)] = (bf16)fmaxf(yp + yq, 0.f);
            }
        }
    }
}

// ---------- meta ----------

__global__ __launch_bounds__(256) void k_meta(
    const bf16* __restrict__ Apre, const float* __restrict__ nodes,
    const bf16* __restrict__ Wg,
    const float* __restrict__ g, const float* __restrict__ bg,
    bf16* __restrict__ featB)
{
    __shared__ __align__(16) bf16 Wl[128 * LP2];
    __shared__ __align__(16) bf16 Al[64 * LP2];
    const int row0 = blockIdx.x * 64;
    stageWB<LP2, 160>(Wg, Wl);
    {
        const int r = threadIdx.x >> 2, q = threadIdx.x & 3;
        float4* d = (float4*)(&Al[r * LP2 + q * 32]);
        const int row = row0 + r;
        if (row < NN) {
            const float4* s = (const float4*)(Apre + (size_t)row * 128 + q * 32);
            float4 a0 = s[0], a1 = s[1], a2 = s[2], a3 = s[3];
            d[0] = a0; d[1] = a1; d[2] = a2; d[3] = a3;
        } else {
            float4 z = {0.f, 0.f, 0.f, 0.f};
            d[0] = z; d[1] = z; d[2] = z; d[3] = z;
        }
    }
    if (threadIdx.x < 64) {
        const int rr = threadIdx.x, row = row0 + rr;
        bf16* d = &Al[rr * LP2 + 128];
        if (row < NN) {
            const float4 x = *(const float4*)(nodes + (size_t)row * 8 + 4);
            d[0] = (bf16)x.x; d[1] = (bf16)x.y; d[2] = (bf16)x.z; d[3] = (bf16)x.w;
        } else {
            d[0] = (bf16)0.f; d[1] = (bf16)0.f; d[2] = (bf16)0.f; d[3] = (bf16)0.f;
        }
#pragma unroll
        for (int c = 4; c < 32; ++c) d[c] = (bf16)0.f;
    }
    __syncthreads();
    const int lane = threadIdx.x & 63, m0 = (threadIdx.x >> 6) * 16;
    f32x4 acc[8]; zacc8(acc);
    mmaT<LP2, 5>(Al, Wl, m0, lane, acc);

    float mean[4], rs[4];
    gnstats(acc, mean, rs);
    float gv[8], bv[8];
#pragma unroll
    for (int n = 0; n < 8; ++n) { const int c = n * 16 + (lane & 15); gv[n] = g[c]; bv[n] = bg[c]; }
#pragma unroll
    for (int r = 0; r < 4; ++r) {
        const int row = row0 + m0 + (lane >> 4) * 4 + r;
        if (row < NN) {
            const size_t off = (size_t)row * 128 + (lane & 15);
#pragma unroll
            for (int n = 0; n < 8; ++n) {
                const float y = (acc[n][r] - mean[r]) * rs[r] * gv[n] + bv[n];
                featB[off + n * 16] = (bf16)fmaxf(y, 0.f);
            }
        }
    }
}

// ---------- fused round: M=128, 512 threads, reg gather, paired tail, post-barrier prefetch ----------

__global__ __launch_bounds__(512, 4) void k_round(
    const bf16* __restrict__ feat,
    const int* __restrict__ ptr,
    const int* __restrict__ sl32,      // u64 elist viewed as int pairs; src = sl32[2*j]
    const bf16* __restrict__ wEdgeR,
    const bf16* __restrict__ wCtrR,
    const bf16* __restrict__ wCtr2R,
    const float* __restrict__ ng, const float* __restrict__ nbg,
    const float* __restrict__ c2g, const float* __restrict__ c2bg,
    bf16* __restrict__ featOut,
    float* __restrict__ outF,
    int last)
{
    __shared__ __align__(16) bf16 WL[2 * 16384];
    const int tid = threadIdx.x;
    const int w = tid >> 6, lane = tid & 63;
    const int r = lane & 15, h = lane >> 4, r7 = r & 7;
    const int m0 = w * 16;
    const int row0 = blockIdx.x * 128;
    const int grow = row0 + m0 + r;            // row this lane gathers (A-side)
    const bool rowok = grow < NN;

    // prologue: async-stage W[0]
    stageW(wEdgeR, WL, w, lane);

    // phase-0 segment (2 srcs) + phase-1 ptr
    int p0 = 0, p1 = 0;
    if (rowok) { p0 = ptr[grow]; p1 = ptr[grow + 1]; }
    int s0 = 0, s1 = 0;
    if (p1 > p0)     s0 = sl32[2 * p0];
    if (p1 > p0 + 1) s1 = sl32[2 * (p0 + 1)];
    int n0 = 0, n1 = 0;
    if (rowok) { n0 = ptr[NN + grow]; n1 = ptr[NN + grow + 1]; }

    f32x4 acc[8]; zacc8(acc);

    for (int t = 0; t < 15; ++t) {
        bf16x8 afr[4];
        if (t < 14) {
            const int d = p1 - p0;
            float ag[4][8];
#pragma unroll
            for (int kk = 0; kk < 4; ++kk)
#pragma unroll
                for (int j = 0; j < 8; ++j) ag[kk][j] = 0.f;
            bf16x8 e0[4], e1[4];
            // head: two independent loads up front
            if (d > 0) loadrow(e0, feat, s0, h);
            if (d > 1) loadrow(e1, feat, s1, h);
            if (d > 0) faccum(ag, e0);
            if (d > 1) faccum(ag, e1);
            // paired tail: 2 loads in flight per step (reuses e0/e1 registers)
            for (int j = p0 + 2; j < p1; j += 2) {
                loadrow(e0, feat, sl32[2 * j], h);
                if (j + 1 < p1) {
                    loadrow(e1, feat, sl32[2 * (j + 1)], h);
                    faccum(ag, e0);
                    faccum(ag, e1);
                } else {
                    faccum(ag, e0);
                }
            }
#pragma unroll
            for (int kk = 0; kk < 4; ++kk)
#pragma unroll
                for (int j = 0; j < 8; ++j) afr[kk][j] = (bf16)ag[kk][j];
        } else {
            // ctr self-term: A = own feat row (already bf16)
            bf16x8 e0[4];
            if (rowok) loadrow(e0, feat, grow, h);
            else { bf16x8 z{}; e0[0] = e0[1] = e0[2] = e0[3] = z; }
#pragma unroll
            for (int kk = 0; kk < 4; ++kk) afr[kk] = e0[kk];
        }
        if (!rowok) { bf16x8 z{}; afr[0] = afr[1] = afr[2] = afr[3] = z; }

        asm volatile("s_waitcnt vmcnt(0)" ::: "memory");   // my gathers + my W[t] chunks landed
        __builtin_amdgcn_s_barrier();                      // all W[t] chunks in; MFMA[t-1] reads done
        __builtin_amdgcn_sched_barrier(0);
        if (t < 13)       stageW(wEdgeR + (size_t)(t + 1) * 16384, WL + ((t + 1) & 1) * 16384, w, lane);
        else if (t == 13) stageW(wCtrR,  WL,          w, lane);   // t=14 uses buf0
        else              stageW(wCtr2R, WL + 16384,  w, lane);   // ctr2 into buf1
        // post-barrier prefetch: t+1 srcs + t+2 ptr overlap the MFMA below,
        // and are NOT in this phase's vmcnt(0) drain path.
        if (t < 13) {
            const int dn = n1 - n0;
            int u0 = 0, u1 = 0;
            if (dn > 0) u0 = sl32[2 * n0];
            if (dn > 1) u1 = sl32[2 * (n0 + 1)];
            int q0 = 0, q1 = 0;
            if (t < 12 && rowok) {
                const size_t b2 = (size_t)(t + 2) * NN + grow;
                q0 = ptr[b2]; q1 = ptr[b2 + 1];
            }
            p0 = n0; p1 = n1; s0 = u0; s1 = u1; n0 = q0; n1 = q1;
        }
        __builtin_amdgcn_sched_barrier(0);
        mmaW(WL + (t & 1) * 16384, afr, r, h, r7, acc);
    }

    // epilogue 1: GN(norm) + relu -> swizzled bf16 A2 tile in buf0
    float mean[4], rsv[4];
    gnstats(acc, mean, rsv);
    float gv[8], bv[8];
#pragma unroll
    for (int n = 0; n < 8; ++n) { const int c = n * 16 + r; gv[n] = ng[c]; bv[n] = nbg[c]; }
    asm volatile("s_waitcnt vmcnt(0)" ::: "memory");   // ctr2 W landed (mine)
    __builtin_amdgcn_s_barrier();                      // all MFMA[14] reads of buf0 done
    __builtin_amdgcn_sched_barrier(0);
#pragma unroll
    for (int r2 = 0; r2 < 4; ++r2) {
        const int lrow = m0 + h * 4 + r2;
#pragma unroll
        for (int n = 0; n < 8; ++n) {
            const float y = (acc[n][r2] - mean[r2]) * rsv[r2] * gv[n] + bv[n];
            const int col = n * 16 + r;
            const int slot = (col >> 3) ^ (lrow & 7);
            *(bf16*)((char*)WL + lrow * 256 + slot * 16 + (col & 7) * 2) = (bf16)fmaxf(y, 0.f);
        }
    }
    asm volatile("s_waitcnt lgkmcnt(0)" ::: "memory");
    __builtin_amdgcn_s_barrier();
    __builtin_amdgcn_sched_barrier(0);

    // phase 2: ctr2 GEMM (A2 from buf0-swizzled, W from buf1)
    bf16x8 afr2[4];
    {
        const int arow = m0 + r;
#pragma unroll
        for (int kk = 0; kk < 4; ++kk) {
            const int slot = (kk * 4 + h) ^ (arow & 7);
            afr2[kk] = *(const bf16x8*)((const char*)WL + arow * 256 + slot * 16);
        }
    }
    zacc8(acc);
    mmaW(WL + 16384, afr2, r, h, r7, acc);

    // epilogue 2: GN(ctr2) + residual(=feat, bf16) + relu
    gnstats(acc, mean, rsv);
#pragma unroll
    for (int n = 0; n < 8; ++n) { const int c = n * 16 + r; gv[n] = c2g[c]; bv[n] = c2bg[c]; }
#pragma unroll
    for (int r2 = 0; r2 < 4; ++r2) {
        const int orow = row0 + m0 + h * 4 + r2;
        if (orow < NN) {
            const size_t off = (size_t)orow * 128 + r;
#pragma unroll
            for (int n = 0; n < 8; ++n) {
                const float y = (acc[n][r2] - mean[r2]) * rsv[r2] * gv[n] + bv[n];
                const float o = fmaxf(y + (float)feat[off + n * 16], 0.f);
                if (last) outF[off + n * 16] = o;
                else      featOut[off + n * 16] = (bf16)o;
            }
        }
    }
}

// ---------- launch ----------

extern "C" void kernel_launch(void* const* d_in, const int* in_sizes, int n_in,
                              void* d_out, int out_size, void* d_ws, size_t ws_size,
                              hipStream_t stream) {
    const float* nodes  = (const float*)d_in[0];
    const int*   idx    = (const int*)d_in[1];
    const int*   mask   = (const int*)d_in[2];
    const float* in1W   = (const float*)d_in[3];
    const float* in1b   = (const float*)d_in[4];
    const float* in2W   = (const float*)d_in[5];
    const float* ing    = (const float*)d_in[6];
    const float* inbg   = (const float*)d_in[7];
    const float* seg1W  = (const float*)d_in[8];
    const float* seg1b  = (const float*)d_in[9];
    const float* seg2W  = (const float*)d_in[10];
    const float* segg   = (const float*)d_in[11];
    const float* segbg  = (const float*)d_in[12];
    const float* metaW  = (const float*)d_in[13];
    const float* metag  = (const float*)d_in[14];
    const float* metabg = (const float*)d_in[15];
    const float* ctrW   = (const float*)d_in[16];
    const float* edgeW  = (const float*)d_in[17];
    const float* normg  = (const float*)d_in[18];
    const float* normbg = (const float*)d_in[19];
    const float* ctr2W  = (const float*)d_in[20];
    const float* ctr2g  = (const float*)d_in[21];
    const float* ctr2bg = (const float*)d_in[22];
    float* out = (float*)d_out;

    char* w = (char*)d_ws;
    bf16*  featB0 = (bf16*)w;  w += (size_t)NN * 128 * 2;
    bf16*  featB1 = (bf16*)w;  w += (size_t)NN * 128 * 2;
    bf16*  preB   = (bf16*)w;  w += (size_t)NN * 128 * 2;
    bf16*  wIn2   = (bf16*)w;  w += 16384 * 2;
    bf16*  wSeg2  = (bf16*)w;  w += 16384 * 2;
    bf16*  wMeta  = (bf16*)w;  w += 20480 * 2;
    bf16*  wCtr   = (bf16*)w;  w += 65536 * 2;
    bf16*  wCtr2  = (bf16*)w;  w += 65536 * 2;
    bf16*  wEdge  = (bf16*)w;  w += (size_t)917504 * 2;
    int*   cnt    = (int*)w;   w += (size_t)NCNT * 4;
    int*   ptr    = (int*)w;   w += ((size_t)NCNT + 4) * 4;
    int*   cursor = (int*)w;   w += (size_t)NCNT * 4;
    u64*   elist  = (u64*)w;   w += (size_t)14 * NE * 8 + 64;
    int*   tot    = (int*)w;   w += (NSCB + 1) * 4;

    dim3 blk(256);
    const int gRows = (NN + 63) / 64;

    // CSR build
    hipMemsetAsync(cnt, 0, (size_t)NCNT * 4, stream);
    k_count<<<2048, blk, 0, stream>>>(idx, mask, cnt);
    k_scanA<<<NSCB, blk, 0, stream>>>(cnt, ptr, tot);
    k_scanB<<<1, 64, 0, stream>>>(tot);
    k_scanC<<<NSCB, blk, 0, stream>>>(ptr, cursor, tot);
    k_fill<<<2048, blk, 0, stream>>>(idx, mask, cursor, elist);
    k_sortseg<<<2048, blk, 0, stream>>>(ptr, elist);

    // weights -> bf16 (+ nodes slice of the output)
    k_cvt_all<<<1024, blk, 0, stream>>>(in2W, seg2W, metaW, ctrW, ctr2W, edgeW,
                                        wIn2, wSeg2, wMeta, wCtr, wCtr2, wEdge,
                                        nodes, out);

    // encoders
    k_in<<<gRows, blk, 0, stream>>>(nodes, in1W, in1b, wIn2, ing, inbg,
                                    seg1W, seg1b, wSeg2, segg, segbg, preB);
    k_meta<<<gRows, blk, 0, stream>>>(preB, nodes, wMeta, metag, metabg, featB0);

    // 4 rounds, ping-pong bf16 feat buffers; last round writes d_out directly
    bf16* bufs[2] = { featB0, featB1 };
    const int gR2 = (NN + 127) / 128;
    for (int i = 0; i < 4; ++i) {
        k_round<<<gR2, dim3(512), 0, stream>>>(bufs[i & 1], ptr, (const int*)elist,
                                               wEdge + (size_t)i * 14 * 16384,
                                               wCtr + (size_t)i * 16384,
                                               wCtr2 + (size_t)i * 16384,
                                               normg + i * 128, normbg + i * 128,
                                               ctr2g + i * 128, ctr2bg + i * 128,
                                               bufs[(i + 1) & 1], out,
                                               i == 3 ? 1 : 0);
    }
}

// Round 7
// 1383.971 us; speedup vs baseline: 1.5442x; 1.5442x over previous
//
#include <hip/hip_runtime.h>
#include <hip/hip_bf16.h>

#define NN 100000
#define NE 100000
#define NCNT (14 * NN)
#define LP 136    // padded LDS pitch (bf16) for encoder kernels
#define LP2 168   // pitch for K=160 (meta)
#define SCAN_CHUNK 4096
#define NSCB ((NCNT + SCAN_CHUNK - 1) / SCAN_CHUNK)

typedef __bf16 bf16;
typedef __bf16 bf16x8 __attribute__((ext_vector_type(8)));
typedef float  f32x4  __attribute__((ext_vector_type(4)));
typedef unsigned long long u64;

// ---------- generic helpers ----------

__device__ __forceinline__ void gl2lds16(const bf16* g, bf16* l) {
    __builtin_amdgcn_global_load_lds(
        (const __attribute__((address_space(1))) void*)g,
        (__attribute__((address_space(3))) void*)l, 16, 0, 0);
}

__device__ __forceinline__ void zacc8(f32x4 acc[8]) {
    f32x4 z = {0.f, 0.f, 0.f, 0.f};
#pragma unroll
    for (int n = 0; n < 8; ++n) acc[n] = z;
}

// per-wave GroupNorm(1) stats: wave holds 16 full rows; rows (lane>>4)*4+r
__device__ __forceinline__ void gnstats(const f32x4 acc[8], float mean[4], float rs[4]) {
    float s1[4], s2[4];
#pragma unroll
    for (int r = 0; r < 4; ++r) { s1[r] = 0.f; s2[r] = 0.f; }
#pragma unroll
    for (int n = 0; n < 8; ++n)
#pragma unroll
        for (int r = 0; r < 4; ++r) { float v = acc[n][r]; s1[r] += v; s2[r] += v * v; }
#pragma unroll
    for (int off = 1; off < 16; off <<= 1) {
#pragma unroll
        for (int r = 0; r < 4; ++r) {
            s1[r] += __shfl_xor(s1[r], off, 64);
            s2[r] += __shfl_xor(s2[r], off, 64);
        }
    }
#pragma unroll
    for (int r = 0; r < 4; ++r) {
        const float m = s1[r] * 0.0078125f;
        const float v = fmaxf(s2[r] * 0.0078125f - m * m, 0.f);
        mean[r] = m;
        rs[r] = rsqrtf(v + 1e-5f);
    }
}

// ---------- encoder-path helpers ----------

template<int PITCH, int COLS>
__device__ inline void stageWB(const bf16* __restrict__ Wg, bf16* Wl) {
    constexpr int NV = 128 * COLS / 8;
    for (int i = threadIdx.x; i < NV; i += 256) {
        const int e = i * 8;
        const int r = e / COLS, c = e % COLS;
        *(float4*)(&Wl[r * PITCH + c]) = ((const float4*)Wg)[i];
    }
}

template<int PITCH, int KSTEPS>
__device__ inline void mmaT(const bf16* Al, const bf16* Wl, int m0, int lane, f32x4 acc[8]) {
#pragma unroll
    for (int kk = 0; kk < KSTEPS; ++kk) {
        bf16x8 a = *(const bf16x8*)(&Al[(m0 + (lane & 15)) * PITCH + kk * 32 + (lane >> 4) * 8]);
#pragma unroll
        for (int n = 0; n < 8; ++n) {
            bf16x8 b = *(const bf16x8*)(&Wl[(n * 16 + (lane & 15)) * PITCH + kk * 32 + (lane >> 4) * 8]);
            acc[n] = __builtin_amdgcn_mfma_f32_16x16x32_bf16(a, b, acc[n], 0, 0, 0);
        }
    }
}

// ---------- k_round helpers (8-wave block, M=128) ----------

// stage one 128x128 bf16 W into WLbase (rows of 256B, slot ^= (row&7) via pre-swizzled src)
// 8 waves x 4 instrs x 1KB = 32KB
__device__ __forceinline__ void stageW(const bf16* __restrict__ Wg, bf16* WLbase,
                                       int w, int lane) {
#pragma unroll
    for (int k = 0; k < 4; ++k) {
        const int R = (w * 4 + k) * 4 + (lane >> 4);
        const int sg = (lane & 15) ^ ((k & 1) * 4 + (lane >> 4));   // == (lane&15) ^ (R&7)
        gl2lds16(Wg + R * 128 + sg * 8, WLbase + (w * 4 + k) * 512);
    }
}

// B-frag reads from swizzled W tile + MFMA
__device__ __forceinline__ void mmaW(const bf16* B, const bf16x8 afr[4],
                                     int r, int h, int r7, f32x4 acc[8]) {
#pragma unroll
    for (int kk = 0; kk < 4; ++kk) {
        const int sl = ((kk * 4 + h) ^ r7) * 8;
#pragma unroll
        for (int n = 0; n < 8; ++n) {
            const bf16x8 b = *(const bf16x8*)(B + (n * 16 + r) * 128 + sl);
            acc[n] = __builtin_amdgcn_mfma_f32_16x16x32_bf16(afr[kk], b, acc[n], 0, 0, 0);
        }
    }
}

__device__ __forceinline__ void loadrow(bf16x8 e[4], const bf16* __restrict__ feat,
                                        int s, int h) {
    const bf16x8* q = (const bf16x8*)(feat + (size_t)s * 128 + h * 8);
    e[0] = q[0]; e[1] = q[4]; e[2] = q[8]; e[3] = q[12];
}

__device__ __forceinline__ void faccum(float ag[4][8], const bf16x8 e[4]) {
#pragma unroll
    for (int kk = 0; kk < 4; ++kk)
#pragma unroll
        for (int j = 0; j < 8; ++j) ag[kk][j] += (float)e[kk][j];
}

// ---------- weight conversion + nodes output slice (one kernel) ----------

__global__ __launch_bounds__(256) void k_cvt_all(
    const float* __restrict__ in2W, const float* __restrict__ seg2W,
    const float* __restrict__ metaW, const float* __restrict__ ctrW,
    const float* __restrict__ ctr2W, const float* __restrict__ edgeW,
    bf16* __restrict__ wIn2, bf16* __restrict__ wSeg2, bf16* __restrict__ wMeta,
    bf16* __restrict__ wCtr, bf16* __restrict__ wCtr2, bf16* __restrict__ wEdge,
    const float* __restrict__ nodes, float* __restrict__ outp)
{
    for (int j = blockIdx.x * 256 + threadIdx.x; j < 2 * NN; j += gridDim.x * 256)
        outp[(size_t)NN * 128 + j] = nodes[(size_t)(j >> 1) * 8 + (j & 1)];
    const int total = 16384 + 16384 + 20480 + 65536 + 65536 + 917504;
    for (int i = blockIdx.x * 256 + threadIdx.x; i < total; i += gridDim.x * 256) {
        int j = i;
        if (j < 16384) { wIn2[j] = (bf16)in2W[j]; continue; }
        j -= 16384;
        if (j < 16384) { wSeg2[j] = (bf16)seg2W[j]; continue; }
        j -= 16384;
        if (j < 20480) {
            const int r = j / 160, c = j % 160;
            wMeta[j] = (bf16)(c < 132 ? metaW[r * 132 + c] : 0.f);
            continue;
        }
        j -= 20480;
        if (j < 65536) { wCtr[j] = (bf16)ctrW[j]; continue; }
        j -= 65536;
        if (j < 65536) { wCtr2[j] = (bf16)ctr2W[j]; continue; }
        j -= 65536;
        wEdge[j] = (bf16)edgeW[j];
    }
}

// ---------- CSR build ----------

__global__ __launch_bounds__(256) void k_count(const int* __restrict__ idx,
                                               const int* __restrict__ mask,
                                               int* __restrict__ cnt) {
    __shared__ int lim[14];
    if (threadIdx.x < 14) lim[threadIdx.x] = min(mask[threadIdx.x], NE);
    __syncthreads();
    for (int i = blockIdx.x * 256 + threadIdx.x; i < 14 * NE; i += gridDim.x * 256) {
        const int e = i / 14, t = i - e * 14;
        if (e < lim[t]) atomicAdd(&cnt[t * NN + idx[(size_t)e * 28 + 2 * t]], 1);
    }
}

__global__ __launch_bounds__(256) void k_scanA(const int* __restrict__ cnt,
                                               int* __restrict__ ptr,
                                               int* __restrict__ tot) {
    __shared__ int sm[256];
    const int tid = threadIdx.x;
    const int base = blockIdx.x * SCAN_CHUNK + tid * 16;
    int v[16]; int run = 0;
#pragma unroll
    for (int j = 0; j < 16; ++j) {
        const int x = (base + j < NCNT) ? cnt[base + j] : 0;
        v[j] = run; run += x;
    }
    sm[tid] = run; __syncthreads();
    for (int d = 1; d < 256; d <<= 1) {
        int t = 0;
        if (tid >= d) t = sm[tid - d];
        __syncthreads();
        sm[tid] += t;
        __syncthreads();
    }
    const int off = sm[tid] - run;
#pragma unroll
    for (int j = 0; j < 16; ++j)
        if (base + j < NCNT) ptr[base + j] = v[j] + off;
    if (tid == 255) tot[blockIdx.x] = sm[255];
}

__global__ void k_scanB(int* __restrict__ tot) {
    if (threadIdx.x == 0 && blockIdx.x == 0) {
        int acc = 0;
        for (int b = 0; b < NSCB; ++b) { const int t = tot[b]; tot[b] = acc; acc += t; }
        tot[NSCB] = acc;
    }
}

__global__ __launch_bounds__(256) void k_scanC(int* __restrict__ ptr,
                                               int* __restrict__ cursor,
                                               const int* __restrict__ tot) {
    const int base = blockIdx.x * SCAN_CHUNK;
    const int o = tot[blockIdx.x];
    for (int j = threadIdx.x; j < SCAN_CHUNK; j += 256) {
        const int i = base + j;
        if (i < NCNT) { const int p = ptr[i] + o; ptr[i] = p; cursor[i] = p; }
    }
    if (blockIdx.x == 0 && threadIdx.x == 0) ptr[NCNT] = tot[NSCB];
}

// elist entry: (edge_id << 32) | src  -> sortable by edge id, src in low word
__global__ __launch_bounds__(256) void k_fill(const int* __restrict__ idx,
                                              const int* __restrict__ mask,
                                              int* __restrict__ cursor,
                                              u64* __restrict__ el) {
    __shared__ int lim[14];
    if (threadIdx.x < 14) lim[threadIdx.x] = min(mask[threadIdx.x], NE);
    __syncthreads();
    for (int i = blockIdx.x * 256 + threadIdx.x; i < 14 * NE; i += gridDim.x * 256) {
        const int e = i / 14, t = i - e * 14;
        if (e < lim[t]) {
            const int dst = idx[(size_t)e * 28 + 2 * t];
            const int src = idx[(size_t)e * 28 + 2 * t + 1];
            const int pos = atomicAdd(&cursor[t * NN + dst], 1);
            el[pos] = ((u64)(unsigned)e << 32) | (unsigned)src;
        }
    }
}

__global__ __launch_bounds__(256) void k_sortseg(const int* __restrict__ ptr,
                                                 u64* __restrict__ el) {
    for (int i = blockIdx.x * 256 + threadIdx.x; i < NCNT; i += gridDim.x * 256) {
        const int s = ptr[i], e2 = ptr[i + 1];
        for (int a = s + 1; a < e2; ++a) {
            const u64 key = el[a];
            int b = a - 1;
            while (b >= s && el[b] > key) { el[b + 1] = el[b]; --b; }
            el[b + 1] = key;
        }
    }
}

// ---------- input encoder ----------

__global__ __launch_bounds__(256) void k_in(
    const float* __restrict__ nodes,
    const float* __restrict__ in1W, const float* __restrict__ in1b,
    const bf16* __restrict__ wIn2,
    const float* __restrict__ ing, const float* __restrict__ inbg,
    const float* __restrict__ seg1W, const float* __restrict__ seg1b,
    const bf16* __restrict__ wSeg2,
    const float* __restrict__ segg, const float* __restrict__ segbg,
    bf16* __restrict__ outPre)
{
    __shared__ __align__(16) bf16 Wl[128 * LP];
    __shared__ __align__(16) bf16 Al[64 * LP];
    __shared__ float w0[128], w1[128], bb[128];
    __shared__ float xs[64][4];
    const int tid = threadIdx.x;
    const int row0 = blockIdx.x * 64;
    if (tid < 64) {
        const int row = row0 + tid;
        float4 x = {0.f, 0.f, 0.f, 0.f};
        if (row < NN) x = *(const float4*)(nodes + (size_t)row * 8);
        xs[tid][0] = x.x; xs[tid][1] = x.y; xs[tid][2] = x.z; xs[tid][3] = x.w;
    }
    if (tid < 128) { w0[tid] = in1W[tid * 2]; w1[tid] = in1W[tid * 2 + 1]; bb[tid] = in1b[tid]; }
    stageWB<LP, 128>(wIn2, Wl);
    __syncthreads();
    for (int i = tid; i < 64 * 128; i += 256) {
        const int r = i >> 7, j = i & 127;
        Al[r * LP + j] = (bf16)fmaxf(xs[r][0] * w0[j] + xs[r][1] * w1[j] + bb[j], 0.f);
    }
    __syncthreads();
    const int lane = tid & 63, m0 = (tid >> 6) * 16;
    f32x4 accP[8]; zacc8(accP);
    mmaT<LP, 4>(Al, Wl, m0, lane, accP);
    __syncthreads();
    if (tid < 128) { w0[tid] = seg1W[tid * 2]; w1[tid] = seg1W[tid * 2 + 1]; bb[tid] = seg1b[tid]; }
    stageWB<LP, 128>(wSeg2, Wl);
    __syncthreads();
    for (int i = tid; i < 64 * 128; i += 256) {
        const int r = i >> 7, j = i & 127;
        Al[r * LP + j] = (bf16)fmaxf(xs[r][2] * w0[j] + xs[r][3] * w1[j] + bb[j], 0.f);
    }
    __syncthreads();
    f32x4 accQ[8]; zacc8(accQ);
    mmaT<LP, 4>(Al, Wl, m0, lane, accQ);

    float mP[4], rP[4], mQ[4], rQ[4];
    gnstats(accP, mP, rP);
    gnstats(accQ, mQ, rQ);
    float gP[8], bP[8], gQ[8], bQ[8];
#pragma unroll
    for (int n = 0; n < 8; ++n) {
        const int c = n * 16 + (lane & 15);
        gP[n] = ing[c]; bP[n] = inbg[c]; gQ[n] = segg[c]; bQ[n] = segbg[c];
    }
#pragma unroll
    for (int r = 0; r < 4; ++r) {
        const int row = row0 + m0 + (lane >> 4) * 4 + r;
        if (row < NN) {
#pragma unroll
            for (int n = 0; n < 8; ++n) {
                const float yp = (accP[n][r] - mP[r]) * rP[r] * gP[n] + bP[n];
                const float yq = (accQ[n][r] - mQ[r]) * rQ[r] * gQ[n] + bQ[n];
                outPre[(size_t)row * 128 + n * 16 + (lane & 15)] = (bf16)fmaxf(yp + yq, 0.f);
            }
        }
    }
}

// ---------- meta ----------

__global__ __launch_bounds__(256) void k_meta(
    const bf16* __restrict__ Apre, const float* __restrict__ nodes,
    const bf16* __restrict__ Wg,
    const float* __restrict__ g, const float* __restrict__ bg,
    bf16* __restrict__ featB)
{
    __shared__ __align__(16) bf16 Wl[128 * LP2];
    __shared__ __align__(16) bf16 Al[64 * LP2];
    const int row0 = blockIdx.x * 64;
    stageWB<LP2, 160>(Wg, Wl);
    {
        const int r = threadIdx.x >> 2, q = threadIdx.x & 3;
        float4* d = (float4*)(&Al[r * LP2 + q * 32]);
        const int row = row0 + r;
        if (row < NN) {
            const float4* s = (const float4*)(Apre + (size_t)row * 128 + q * 32);
            float4 a0 = s[0], a1 = s[1], a2 = s[2], a3 = s[3];
            d[0] = a0; d[1] = a1; d[2] = a2; d[3] = a3;
        } else {
            float4 z = {0.f, 0.f, 0.f, 0.f};
            d[0] = z; d[1] = z; d[2] = z; d[3] = z;
        }
    }
    if (threadIdx.x < 64) {
        const int rr = threadIdx.x, row = row0 + rr;
        bf16* d = &Al[rr * LP2 + 128];
        if (row < NN) {
            const float4 x = *(const float4*)(nodes + (size_t)row * 8 + 4);
            d[0] = (bf16)x.x; d[1] = (bf16)x.y; d[2] = (bf16)x.z; d[3] = (bf16)x.w;
        } else {
            d[0] = (bf16)0.f; d[1] = (bf16)0.f; d[2] = (bf16)0.f; d[3] = (bf16)0.f;
        }
#pragma unroll
        for (int c = 4; c < 32; ++c) d[c] = (bf16)0.f;
    }
    __syncthreads();
    const int lane = threadIdx.x & 63, m0 = (threadIdx.x >> 6) * 16;
    f32x4 acc[8]; zacc8(acc);
    mmaT<LP2, 5>(Al, Wl, m0, lane, acc);

    float mean[4], rs[4];
    gnstats(acc, mean, rs);
    float gv[8], bv[8];
#pragma unroll
    for (int n = 0; n < 8; ++n) { const int c = n * 16 + (lane & 15); gv[n] = g[c]; bv[n] = bg[c]; }
#pragma unroll
    for (int r = 0; r < 4; ++r) {
        const int row = row0 + m0 + (lane >> 4) * 4 + r;
        if (row < NN) {
            const size_t off = (size_t)row * 128 + (lane & 15);
#pragma unroll
            for (int n = 0; n < 8; ++n) {
                const float y = (acc[n][r] - mean[r]) * rs[r] * gv[n] + bv[n];
                featB[off + n * 16] = (bf16)fmaxf(y, 0.f);
            }
        }
    }
}

// ---------- fused round: M=128, 512 threads, reg gather, paired tail, post-barrier prefetch ----------
// __launch_bounds__(512, 2): LDS (64KB) caps residency at 2 blocks/CU anyway;
// requesting 4 capped VGPRs at 64 and spilled the gather pipeline (r5/r6 regression).

__global__ __launch_bounds__(512, 2) void k_round(
    const bf16* __restrict__ feat,
    const int* __restrict__ ptr,
    const int* __restrict__ sl32,      // u64 elist viewed as int pairs; src = sl32[2*j]
    const bf16* __restrict__ wEdgeR,
    const bf16* __restrict__ wCtrR,
    const bf16* __restrict__ wCtr2R,
    const float* __restrict__ ng, const float* __restrict__ nbg,
    const float* __restrict__ c2g, const float* __restrict__ c2bg,
    bf16* __restrict__ featOut,
    float* __restrict__ outF,
    int last)
{
    __shared__ __align__(16) bf16 WL[2 * 16384];
    const int tid = threadIdx.x;
    const int w = tid >> 6, lane = tid & 63;
    const int r = lane & 15, h = lane >> 4, r7 = r & 7;
    const int m0 = w * 16;
    const int row0 = blockIdx.x * 128;
    const int grow = row0 + m0 + r;            // row this lane gathers (A-side)
    const bool rowok = grow < NN;

    // prologue: async-stage W[0]
    stageW(wEdgeR, WL, w, lane);

    // phase-0 segment (2 srcs) + phase-1 ptr
    int p0 = 0, p1 = 0;
    if (rowok) { p0 = ptr[grow]; p1 = ptr[grow + 1]; }
    int s0 = 0, s1 = 0;
    if (p1 > p0)     s0 = sl32[2 * p0];
    if (p1 > p0 + 1) s1 = sl32[2 * (p0 + 1)];
    int n0 = 0, n1 = 0;
    if (rowok) { n0 = ptr[NN + grow]; n1 = ptr[NN + grow + 1]; }

    f32x4 acc[8]; zacc8(acc);

    for (int t = 0; t < 15; ++t) {
        bf16x8 afr[4];
        if (t < 14) {
            const int d = p1 - p0;
            float ag[4][8];
#pragma unroll
            for (int kk = 0; kk < 4; ++kk)
#pragma unroll
                for (int j = 0; j < 8; ++j) ag[kk][j] = 0.f;
            bf16x8 e0[4], e1[4];
            // head: two independent loads up front
            if (d > 0) loadrow(e0, feat, s0, h);
            if (d > 1) loadrow(e1, feat, s1, h);
            if (d > 0) faccum(ag, e0);
            if (d > 1) faccum(ag, e1);
            // paired tail: 2 loads in flight per step (reuses e0/e1 registers)
            for (int j = p0 + 2; j < p1; j += 2) {
                loadrow(e0, feat, sl32[2 * j], h);
                if (j + 1 < p1) {
                    loadrow(e1, feat, sl32[2 * (j + 1)], h);
                    faccum(ag, e0);
                    faccum(ag, e1);
                } else {
                    faccum(ag, e0);
                }
            }
#pragma unroll
            for (int kk = 0; kk < 4; ++kk)
#pragma unroll
                for (int j = 0; j < 8; ++j) afr[kk][j] = (bf16)ag[kk][j];
        } else {
            // ctr self-term: A = own feat row (already bf16)
            bf16x8 e0[4];
            if (rowok) loadrow(e0, feat, grow, h);
            else { bf16x8 z{}; e0[0] = e0[1] = e0[2] = e0[3] = z; }
#pragma unroll
            for (int kk = 0; kk < 4; ++kk) afr[kk] = e0[kk];
        }
        if (!rowok) { bf16x8 z{}; afr[0] = afr[1] = afr[2] = afr[3] = z; }

        asm volatile("s_waitcnt vmcnt(0)" ::: "memory");   // my gathers + my W[t] chunks landed
        __builtin_amdgcn_s_barrier();                      // all W[t] chunks in; MFMA[t-1] reads done
        __builtin_amdgcn_sched_barrier(0);
        if (t < 13)       stageW(wEdgeR + (size_t)(t + 1) * 16384, WL + ((t + 1) & 1) * 16384, w, lane);
        else if (t == 13) stageW(wCtrR,  WL,          w, lane);   // t=14 uses buf0
        else              stageW(wCtr2R, WL + 16384,  w, lane);   // ctr2 into buf1
        // post-barrier prefetch: t+1 srcs + t+2 ptr overlap the MFMA below,
        // and are NOT in this phase's vmcnt(0) drain path.
        if (t < 13) {
            const int dn = n1 - n0;
            int u0 = 0, u1 = 0;
            if (dn > 0) u0 = sl32[2 * n0];
            if (dn > 1) u1 = sl32[2 * (n0 + 1)];
            int q0 = 0, q1 = 0;
            if (t < 12 && rowok) {
                const size_t b2 = (size_t)(t + 2) * NN + grow;
                q0 = ptr[b2]; q1 = ptr[b2 + 1];
            }
            p0 = n0; p1 = n1; s0 = u0; s1 = u1; n0 = q0; n1 = q1;
        }
        __builtin_amdgcn_sched_barrier(0);
        mmaW(WL + (t & 1) * 16384, afr, r, h, r7, acc);
    }

    // epilogue 1: GN(norm) + relu -> swizzled bf16 A2 tile in buf0
    float mean[4], rsv[4];
    gnstats(acc, mean, rsv);
    float gv[8], bv[8];
#pragma unroll
    for (int n = 0; n < 8; ++n) { const int c = n * 16 + r; gv[n] = ng[c]; bv[n] = nbg[c]; }
    asm volatile("s_waitcnt vmcnt(0)" ::: "memory");   // ctr2 W landed (mine)
    __builtin_amdgcn_s_barrier();                      // all MFMA[14] reads of buf0 done
    __builtin_amdgcn_sched_barrier(0);
#pragma unroll
    for (int r2 = 0; r2 < 4; ++r2) {
        const int lrow = m0 + h * 4 + r2;
#pragma unroll
        for (int n = 0; n < 8; ++n) {
            const float y = (acc[n][r2] - mean[r2]) * rsv[r2] * gv[n] + bv[n];
            const int col = n * 16 + r;
            const int slot = (col >> 3) ^ (lrow & 7);
            *(bf16*)((char*)WL + lrow * 256 + slot * 16 + (col & 7) * 2) = (bf16)fmaxf(y, 0.f);
        }
    }
    asm volatile("s_waitcnt lgkmcnt(0)" ::: "memory");
    __builtin_amdgcn_s_barrier();
    __builtin_amdgcn_sched_barrier(0);

    // phase 2: ctr2 GEMM (A2 from buf0-swizzled, W from buf1)
    bf16x8 afr2[4];
    {
        const int arow = m0 + r;
#pragma unroll
        for (int kk = 0; kk < 4; ++kk) {
            const int slot = (kk * 4 + h) ^ (arow & 7);
            afr2[kk] = *(const bf16x8*)((const char*)WL + arow * 256 + slot * 16);
        }
    }
    zacc8(acc);
    mmaW(WL + 16384, afr2, r, h, r7, acc);

    // epilogue 2: GN(ctr2) + residual(=feat, bf16) + relu
    gnstats(acc, mean, rsv);
#pragma unroll
    for (int n = 0; n < 8; ++n) { const int c = n * 16 + r; gv[n] = c2g[c]; bv[n] = c2bg[c]; }
#pragma unroll
    for (int r2 = 0; r2 < 4; ++r2) {
        const int orow = row0 + m0 + h * 4 + r2;
        if (orow < NN) {
            const size_t off = (size_t)orow * 128 + r;
#pragma unroll
            for (int n = 0; n < 8; ++n) {
                const float y = (acc[n][r2] - mean[r2]) * rsv[r2] * gv[n] + bv[n];
                const float o = fmaxf(y + (float)feat[off + n * 16], 0.f);
                if (last) outF[off + n * 16] = o;
                else      featOut[off + n * 16] = (bf16)o;
            }
        }
    }
}

// ---------- launch ----------

extern "C" void kernel_launch(void* const* d_in, const int* in_sizes, int n_in,
                              void* d_out, int out_size, void* d_ws, size_t ws_size,
                              hipStream_t stream) {
    const float* nodes  = (const float*)d_in[0];
    const int*   idx    = (const int*)d_in[1];
    const int*   mask   = (const int*)d_in[2];
    const float* in1W   = (const float*)d_in[3];
    const float* in1b   = (const float*)d_in[4];
    const float* in2W   = (const float*)d_in[5];
    const float* ing    = (const float*)d_in[6];
    const float* inbg   = (const float*)d_in[7];
    const float* seg1W  = (const float*)d_in[8];
    const float* seg1b  = (const float*)d_in[9];
    const float* seg2W  = (const float*)d_in[10];
    const float* segg   = (const float*)d_in[11];
    const float* segbg  = (const float*)d_in[12];
    const float* metaW  = (const float*)d_in[13];
    const float* metag  = (const float*)d_in[14];
    const float* metabg = (const float*)d_in[15];
    const float* ctrW   = (const float*)d_in[16];
    const float* edgeW  = (const float*)d_in[17];
    const float* normg  = (const float*)d_in[18];
    const float* normbg = (const float*)d_in[19];
    const float* ctr2W  = (const float*)d_in[20];
    const float* ctr2g  = (const float*)d_in[21];
    const float* ctr2bg = (const float*)d_in[22];
    float* out = (float*)d_out;

    char* w = (char*)d_ws;
    bf16*  featB0 = (bf16*)w;  w += (size_t)NN * 128 * 2;
    bf16*  featB1 = (bf16*)w;  w += (size_t)NN * 128 * 2;
    bf16*  preB   = (bf16*)w;  w += (size_t)NN * 128 * 2;
    bf16*  wIn2   = (bf16*)w;  w += 16384 * 2;
    bf16*  wSeg2  = (bf16*)w;  w += 16384 * 2;
    bf16*  wMeta  = (bf16*)w;  w += 20480 * 2;
    bf16*  wCtr   = (bf16*)w;  w += 65536 * 2;
    bf16*  wCtr2  = (bf16*)w;  w += 65536 * 2;
    bf16*  wEdge  = (bf16*)w;  w += (size_t)917504 * 2;
    int*   cnt    = (int*)w;   w += (size_t)NCNT * 4;
    int*   ptr    = (int*)w;   w += ((size_t)NCNT + 4) * 4;
    int*   cursor = (int*)w;   w += (size_t)NCNT * 4;
    u64*   elist  = (u64*)w;   w += (size_t)14 * NE * 8 + 64;
    int*   tot    = (int*)w;   w += (NSCB + 1) * 4;

    dim3 blk(256);
    const int gRows = (NN + 63) / 64;

    // CSR build
    hipMemsetAsync(cnt, 0, (size_t)NCNT * 4, stream);
    k_count<<<2048, blk, 0, stream>>>(idx, mask, cnt);
    k_scanA<<<NSCB, blk, 0, stream>>>(cnt, ptr, tot);
    k_scanB<<<1, 64, 0, stream>>>(tot);
    k_scanC<<<NSCB, blk, 0, stream>>>(ptr, cursor, tot);
    k_fill<<<2048, blk, 0, stream>>>(idx, mask, cursor, elist);
    k_sortseg<<<2048, blk, 0, stream>>>(ptr, elist);

    // weights -> bf16 (+ nodes slice of the output)
    k_cvt_all<<<1024, blk, 0, stream>>>(in2W, seg2W, metaW, ctrW, ctr2W, edgeW,
                                        wIn2, wSeg2, wMeta, wCtr, wCtr2, wEdge,
                                        nodes, out);

    // encoders
    k_in<<<gRows, blk, 0, stream>>>(nodes, in1W, in1b, wIn2, ing, inbg,
                                    seg1W, seg1b, wSeg2, segg, segbg, preB);
    k_meta<<<gRows, blk, 0, stream>>>(preB, nodes, wMeta, metag, metabg, featB0);

    // 4 rounds, ping-pong bf16 feat buffers; last round writes d_out directly
    bf16* bufs[2] = { featB0, featB1 };
    const int gR2 = (NN + 127) / 128;
    for (int i = 0; i < 4; ++i) {
        k_round<<<gR2, dim3(512), 0, stream>>>(bufs[i & 1], ptr, (const int*)elist,
                                               wEdge + (size_t)i * 14 * 16384,
                                               wCtr + (size_t)i * 16384,
                                               wCtr2 + (size_t)i * 16384,
                                               normg + i * 128, normbg + i * 128,
                                               ctr2g + i * 128, ctr2bg + i * 128,
                                               bufs[(i + 1) & 1], out,
                                               i == 3 ? 1 : 0);
    }
}

// Round 8
// 1371.203 us; speedup vs baseline: 1.5586x; 1.0093x over previous
//
#include <hip/hip_runtime.h>
#include <hip/hip_bf16.h>

#define NN 100000
#define NE 100000
#define NCNT (14 * NN)
#define LP 136    // padded LDS pitch (bf16) for encoder kernels
#define LP2 168   // pitch for K=160 (meta)
#define SCAN_CHUNK 4096
#define NSCB ((NCNT + SCAN_CHUNK - 1) / SCAN_CHUNK)

typedef __bf16 bf16;
typedef __bf16 bf16x8 __attribute__((ext_vector_type(8)));
typedef float  f32x4  __attribute__((ext_vector_type(4)));
typedef unsigned long long u64;

// ---------- generic helpers ----------

__device__ __forceinline__ void zacc8(f32x4 acc[8]) {
    f32x4 z = {0.f, 0.f, 0.f, 0.f};
#pragma unroll
    for (int n = 0; n < 8; ++n) acc[n] = z;
}

// per-wave GroupNorm(1) stats (encoder kernels): wave holds 16 full rows
__device__ __forceinline__ void gnstats(const f32x4 acc[8], float mean[4], float rs[4]) {
    float s1[4], s2[4];
#pragma unroll
    for (int r = 0; r < 4; ++r) { s1[r] = 0.f; s2[r] = 0.f; }
#pragma unroll
    for (int n = 0; n < 8; ++n)
#pragma unroll
        for (int r = 0; r < 4; ++r) { float v = acc[n][r]; s1[r] += v; s2[r] += v * v; }
#pragma unroll
    for (int off = 1; off < 16; off <<= 1) {
#pragma unroll
        for (int r = 0; r < 4; ++r) {
            s1[r] += __shfl_xor(s1[r], off, 64);
            s2[r] += __shfl_xor(s2[r], off, 64);
        }
    }
#pragma unroll
    for (int r = 0; r < 4; ++r) {
        const float m = s1[r] * 0.0078125f;
        const float v = fmaxf(s2[r] * 0.0078125f - m * m, 0.f);
        mean[r] = m;
        rs[r] = rsqrtf(v + 1e-5f);
    }
}

// ---------- encoder-path helpers ----------

template<int PITCH, int COLS>
__device__ inline void stageWB(const bf16* __restrict__ Wg, bf16* Wl) {
    constexpr int NV = 128 * COLS / 8;
    for (int i = threadIdx.x; i < NV; i += 256) {
        const int e = i * 8;
        const int r = e / COLS, c = e % COLS;
        *(float4*)(&Wl[r * PITCH + c]) = ((const float4*)Wg)[i];
    }
}

template<int PITCH, int KSTEPS>
__device__ inline void mmaT(const bf16* Al, const bf16* Wl, int m0, int lane, f32x4 acc[8]) {
#pragma unroll
    for (int kk = 0; kk < KSTEPS; ++kk) {
        bf16x8 a = *(const bf16x8*)(&Al[(m0 + (lane & 15)) * PITCH + kk * 32 + (lane >> 4) * 8]);
#pragma unroll
        for (int n = 0; n < 8; ++n) {
            bf16x8 b = *(const bf16x8*)(&Wl[(n * 16 + (lane & 15)) * PITCH + kk * 32 + (lane >> 4) * 8]);
            acc[n] = __builtin_amdgcn_mfma_f32_16x16x32_bf16(a, b, acc[n], 0, 0, 0);
        }
    }
}

// ---------- weight conversion + nodes output slice (one kernel) ----------

__global__ __launch_bounds__(256) void k_cvt_all(
    const float* __restrict__ in2W, const float* __restrict__ seg2W,
    const float* __restrict__ metaW, const float* __restrict__ ctrW,
    const float* __restrict__ ctr2W, const float* __restrict__ edgeW,
    bf16* __restrict__ wIn2, bf16* __restrict__ wSeg2, bf16* __restrict__ wMeta,
    bf16* __restrict__ wCtr, bf16* __restrict__ wCtr2, bf16* __restrict__ wEdge,
    const float* __restrict__ nodes, float* __restrict__ outp)
{
    for (int j = blockIdx.x * 256 + threadIdx.x; j < 2 * NN; j += gridDim.x * 256)
        outp[(size_t)NN * 128 + j] = nodes[(size_t)(j >> 1) * 8 + (j & 1)];
    const int total = 16384 + 16384 + 20480 + 65536 + 65536 + 917504;
    for (int i = blockIdx.x * 256 + threadIdx.x; i < total; i += gridDim.x * 256) {
        int j = i;
        if (j < 16384) { wIn2[j] = (bf16)in2W[j]; continue; }
        j -= 16384;
        if (j < 16384) { wSeg2[j] = (bf16)seg2W[j]; continue; }
        j -= 16384;
        if (j < 20480) {
            const int r = j / 160, c = j % 160;
            wMeta[j] = (bf16)(c < 132 ? metaW[r * 132 + c] : 0.f);
            continue;
        }
        j -= 20480;
        if (j < 65536) { wCtr[j] = (bf16)ctrW[j]; continue; }
        j -= 65536;
        if (j < 65536) { wCtr2[j] = (bf16)ctr2W[j]; continue; }
        j -= 65536;
        wEdge[j] = (bf16)edgeW[j];
    }
}

// ---------- CSR build ----------

__global__ __launch_bounds__(256) void k_count(const int* __restrict__ idx,
                                               const int* __restrict__ mask,
                                               int* __restrict__ cnt) {
    __shared__ int lim[14];
    if (threadIdx.x < 14) lim[threadIdx.x] = min(mask[threadIdx.x], NE);
    __syncthreads();
    for (int i = blockIdx.x * 256 + threadIdx.x; i < 14 * NE; i += gridDim.x * 256) {
        const int e = i / 14, t = i - e * 14;
        if (e < lim[t]) atomicAdd(&cnt[t * NN + idx[(size_t)e * 28 + 2 * t]], 1);
    }
}

__global__ __launch_bounds__(256) void k_scanA(const int* __restrict__ cnt,
                                               int* __restrict__ ptr,
                                               int* __restrict__ tot) {
    __shared__ int sm[256];
    const int tid = threadIdx.x;
    const int base = blockIdx.x * SCAN_CHUNK + tid * 16;
    int v[16]; int run = 0;
#pragma unroll
    for (int j = 0; j < 16; ++j) {
        const int x = (base + j < NCNT) ? cnt[base + j] : 0;
        v[j] = run; run += x;
    }
    sm[tid] = run; __syncthreads();
    for (int d = 1; d < 256; d <<= 1) {
        int t = 0;
        if (tid >= d) t = sm[tid - d];
        __syncthreads();
        sm[tid] += t;
        __syncthreads();
    }
    const int off = sm[tid] - run;
#pragma unroll
    for (int j = 0; j < 16; ++j)
        if (base + j < NCNT) ptr[base + j] = v[j] + off;
    if (tid == 255) tot[blockIdx.x] = sm[255];
}

__global__ void k_scanB(int* __restrict__ tot) {
    if (threadIdx.x == 0 && blockIdx.x == 0) {
        int acc = 0;
        for (int b = 0; b < NSCB; ++b) { const int t = tot[b]; tot[b] = acc; acc += t; }
        tot[NSCB] = acc;
    }
}

__global__ __launch_bounds__(256) void k_scanC(int* __restrict__ ptr,
                                               int* __restrict__ cursor,
                                               const int* __restrict__ tot) {
    const int base = blockIdx.x * SCAN_CHUNK;
    const int o = tot[blockIdx.x];
    for (int j = threadIdx.x; j < SCAN_CHUNK; j += 256) {
        const int i = base + j;
        if (i < NCNT) { const int p = ptr[i] + o; ptr[i] = p; cursor[i] = p; }
    }
    if (blockIdx.x == 0 && threadIdx.x == 0) ptr[NCNT] = tot[NSCB];
}

// elist entry: (edge_id << 32) | src
__global__ __launch_bounds__(256) void k_fill(const int* __restrict__ idx,
                                              const int* __restrict__ mask,
                                              int* __restrict__ cursor,
                                              u64* __restrict__ el) {
    __shared__ int lim[14];
    if (threadIdx.x < 14) lim[threadIdx.x] = min(mask[threadIdx.x], NE);
    __syncthreads();
    for (int i = blockIdx.x * 256 + threadIdx.x; i < 14 * NE; i += gridDim.x * 256) {
        const int e = i / 14, t = i - e * 14;
        if (e < lim[t]) {
            const int dst = idx[(size_t)e * 28 + 2 * t];
            const int src = idx[(size_t)e * 28 + 2 * t + 1];
            const int pos = atomicAdd(&cursor[t * NN + dst], 1);
            el[pos] = ((u64)(unsigned)e << 32) | (unsigned)src;
        }
    }
}

__global__ __launch_bounds__(256) void k_sortseg(const int* __restrict__ ptr,
                                                 u64* __restrict__ el) {
    for (int i = blockIdx.x * 256 + threadIdx.x; i < NCNT; i += gridDim.x * 256) {
        const int s = ptr[i], e2 = ptr[i + 1];
        for (int a = s + 1; a < e2; ++a) {
            const u64 key = el[a];
            int b = a - 1;
            while (b >= s && el[b] > key) { el[b + 1] = el[b]; --b; }
            el[b + 1] = key;
        }
    }
}

// ---------- input encoder ----------

__global__ __launch_bounds__(256) void k_in(
    const float* __restrict__ nodes,
    const float* __restrict__ in1W, const float* __restrict__ in1b,
    const bf16* __restrict__ wIn2,
    const float* __restrict__ ing, const float* __restrict__ inbg,
    const float* __restrict__ seg1W, const float* __restrict__ seg1b,
    const bf16* __restrict__ wSeg2,
    const float* __restrict__ segg, const float* __restrict__ segbg,
    bf16* __restrict__ outPre)
{
    __shared__ __align__(16) bf16 Wl[128 * LP];
    __shared__ __align__(16) bf16 Al[64 * LP];
    __shared__ float w0[128], w1[128], bb[128];
    __shared__ float xs[64][4];
    const int tid = threadIdx.x;
    const int row0 = blockIdx.x * 64;
    if (tid < 64) {
        const int row = row0 + tid;
        float4 x = {0.f, 0.f, 0.f, 0.f};
        if (row < NN) x = *(const float4*)(nodes + (size_t)row * 8);
        xs[tid][0] = x.x; xs[tid][1] = x.y; xs[tid][2] = x.z; xs[tid][3] = x.w;
    }
    if (tid < 128) { w0[tid] = in1W[tid * 2]; w1[tid] = in1W[tid * 2 + 1]; bb[tid] = in1b[tid]; }
    stageWB<LP, 128>(wIn2, Wl);
    __syncthreads();
    for (int i = tid; i < 64 * 128; i += 256) {
        const int r = i >> 7, j = i & 127;
        Al[r * LP + j] = (bf16)fmaxf(xs[r][0] * w0[j] + xs[r][1] * w1[j] + bb[j], 0.f);
    }
    __syncthreads();
    const int lane = tid & 63, m0 = (tid >> 6) * 16;
    f32x4 accP[8]; zacc8(accP);
    mmaT<LP, 4>(Al, Wl, m0, lane, accP);
    __syncthreads();
    if (tid < 128) { w0[tid] = seg1W[tid * 2]; w1[tid] = seg1W[tid * 2 + 1]; bb[tid] = seg1b[tid]; }
    stageWB<LP, 128>(wSeg2, Wl);
    __syncthreads();
    for (int i = tid; i < 64 * 128; i += 256) {
        const int r = i >> 7, j = i & 127;
        Al[r * LP + j] = (bf16)fmaxf(xs[r][2] * w0[j] + xs[r][3] * w1[j] + bb[j], 0.f);
    }
    __syncthreads();
    f32x4 accQ[8]; zacc8(accQ);
    mmaT<LP, 4>(Al, Wl, m0, lane, accQ);

    float mP[4], rP[4], mQ[4], rQ[4];
    gnstats(accP, mP, rP);
    gnstats(accQ, mQ, rQ);
    float gP[8], bP[8], gQ[8], bQ[8];
#pragma unroll
    for (int n = 0; n < 8; ++n) {
        const int c = n * 16 + (lane & 15);
        gP[n] = ing[c]; bP[n] = inbg[c]; gQ[n] = segg[c]; bQ[n] = segbg[c];
    }
#pragma unroll
    for (int r = 0; r < 4; ++r) {
        const int row = row0 + m0 + (lane >> 4) * 4 + r;
        if (row < NN) {
#pragma unroll
            for (int n = 0; n < 8; ++n) {
                const float yp = (accP[n][r] - mP[r]) * rP[r] * gP[n] + bP[n];
                const float yq = (accQ[n][r] - mQ[r]) * rQ[r] * gQ[n] + bQ[n];
                outPre[(size_t)row * 128 + n * 16 + (lane & 15)] = (bf16)fmaxf(yp + yq, 0.f);
            }
        }
    }
}

// ---------- meta ----------

__global__ __launch_bounds__(256) void k_meta(
    const bf16* __restrict__ Apre, const float* __restrict__ nodes,
    const bf16* __restrict__ Wg,
    const float* __restrict__ g, const float* __restrict__ bg,
    bf16* __restrict__ featB)
{
    __shared__ __align__(16) bf16 Wl[128 * LP2];
    __shared__ __align__(16) bf16 Al[64 * LP2];
    const int row0 = blockIdx.x * 64;
    stageWB<LP2, 160>(Wg, Wl);
    {
        const int r = threadIdx.x >> 2, q = threadIdx.x & 3;
        float4* d = (float4*)(&Al[r * LP2 + q * 32]);
        const int row = row0 + r;
        if (row < NN) {
            const float4* s = (const float4*)(Apre + (size_t)row * 128 + q * 32);
            float4 a0 = s[0], a1 = s[1], a2 = s[2], a3 = s[3];
            d[0] = a0; d[1] = a1; d[2] = a2; d[3] = a3;
        } else {
            float4 z = {0.f, 0.f, 0.f, 0.f};
            d[0] = z; d[1] = z; d[2] = z; d[3] = z;
        }
    }
    if (threadIdx.x < 64) {
        const int rr = threadIdx.x, row = row0 + rr;
        bf16* d = &Al[rr * LP2 + 128];
        if (row < NN) {
            const float4 x = *(const float4*)(nodes + (size_t)row * 8 + 4);
            d[0] = (bf16)x.x; d[1] = (bf16)x.y; d[2] = (bf16)x.z; d[3] = (bf16)x.w;
        } else {
            d[0] = (bf16)0.f; d[1] = (bf16)0.f; d[2] = (bf16)0.f; d[3] = (bf16)0.f;
        }
#pragma unroll
        for (int c = 4; c < 32; ++c) d[c] = (bf16)0.f;
    }
    __syncthreads();
    const int lane = threadIdx.x & 63, m0 = (threadIdx.x >> 6) * 16;
    f32x4 acc[8]; zacc8(acc);
    mmaT<LP2, 5>(Al, Wl, m0, lane, acc);

    float mean[4], rs[4];
    gnstats(acc, mean, rs);
    float gv[8], bv[8];
#pragma unroll
    for (int n = 0; n < 8; ++n) { const int c = n * 16 + (lane & 15); gv[n] = g[c]; bv[n] = bg[c]; }
#pragma unroll
    for (int r = 0; r < 4; ++r) {
        const int row = row0 + m0 + (lane >> 4) * 4 + r;
        if (row < NN) {
            const size_t off = (size_t)row * 128 + (lane & 15);
#pragma unroll
            for (int n = 0; n < 8; ++n) {
                const float y = (acc[n][r] - mean[r]) * rs[r] * gv[n] + bv[n];
                featB[off + n * 16] = (bf16)fmaxf(y, 0.f);
            }
        }
    }
}

// ---------- fused round, restructured ----------
// M=64/block, 512 threads = 8 waves; wave w owns output cols w*16..w*16+15.
// B fragments loaded straight from global (W is L2-hot) -> no W LDS, no DMA.
// Gathered A tile (16KB) goes through LDS double-buffered, 1 barrier/phase.
// GroupNorm via cross-wave LDS reduction (rows are split across waves).

__global__ __launch_bounds__(512, 4) void k_round(
    const bf16* __restrict__ feat,
    const int* __restrict__ ptr,
    const int* __restrict__ sl32,      // u64 elist as int pairs; src = sl32[2*j]
    const bf16* __restrict__ wEdgeR,   // 14 * 16384
    const bf16* __restrict__ wCtrR,
    const bf16* __restrict__ wCtr2R,
    const float* __restrict__ ng, const float* __restrict__ nbg,
    const float* __restrict__ c2g, const float* __restrict__ c2bg,
    bf16* __restrict__ featOut,
    float* __restrict__ outF,
    int last)
{
    __shared__ __align__(16) bf16 AT[2][64 * 128];   // 2 x 16KB A tiles
    __shared__ float red[8 * 64 * 2];                // per-wave GN partials
    __shared__ float stats[64 * 2];                  // mean, rsqrt per row

    const int tid = threadIdx.x;
    const int w = tid >> 6, lane = tid & 63;
    const int r = lane & 15, h = lane >> 4, r7 = r & 7;
    const int n0 = w * 16;                 // wave's output column base
    const int row0 = blockIdx.x * 64;

    // gather role: 8 threads per row, 32B (16 bf16) slice each
    const int rr = tid >> 3, sl = tid & 7;
    const int grow = row0 + rr;
    const bool rowok = grow < NN;
    const int wb0 = rr * 256 + (((2 * sl)     ^ (rr & 7)) * 16);
    const int wb1 = rr * 256 + (((2 * sl + 1) ^ (rr & 7)) * 16);

    // CSR prefetch: segment for t=0, ptr for t=1
    int p0 = 0, p1 = 0;
    if (rowok) { p0 = ptr[grow]; p1 = ptr[grow + 1]; }
    int s0 = 0, s1 = 0;
    if (p1 > p0)     s0 = sl32[2 * p0];
    if (p1 > p0 + 1) s1 = sl32[2 * (p0 + 1)];
    int np0 = 0, np1 = 0;
    if (rowok) { np0 = ptr[NN + grow]; np1 = ptr[NN + grow + 1]; }

    f32x4 acc[4];
    { f32x4 z = {0.f, 0.f, 0.f, 0.f}; acc[0] = z; acc[1] = z; acc[2] = z; acc[3] = z; }

    const char* fb = (const char*)feat;

    for (int t = 0; t < 15; ++t) {
        // B fragments for this phase: straight from global (L2-hot weights)
        const bf16* Wt = (t < 14) ? (wEdgeR + (size_t)t * 16384) : wCtrR;
        bf16x8 bfr[4];
#pragma unroll
        for (int kk = 0; kk < 4; ++kk)
            bfr[kk] = *(const bf16x8*)(Wt + (n0 + r) * 128 + kk * 32 + h * 8);

        bf16x8 av0, av1;
        if (t < 14) {
            const int d = p1 - p0;
            bf16x8 ea0, ea1, eb0, eb1;
            if (d > 0) { const bf16x8* q = (const bf16x8*)(fb + (size_t)s0 * 256 + sl * 32); ea0 = q[0]; ea1 = q[1]; }
            if (d > 1) { const bf16x8* q = (const bf16x8*)(fb + (size_t)s1 * 256 + sl * 32); eb0 = q[0]; eb1 = q[1]; }
            // prefetch t+1 srcs + t+2 ptr (issued early; complete during gather)
            int u0 = 0, u1 = 0, q0 = 0, q1 = 0;
            if (t < 13) {
                const int dn = np1 - np0;
                if (dn > 0) u0 = sl32[2 * np0];
                if (dn > 1) u1 = sl32[2 * (np0 + 1)];
                if (t < 12 && rowok) {
                    const size_t b2 = (size_t)(t + 2) * NN + grow;
                    q0 = ptr[b2]; q1 = ptr[b2 + 1];
                }
            }
            float ag[16];
#pragma unroll
            for (int j = 0; j < 16; ++j) ag[j] = 0.f;
            if (d > 0) {
#pragma unroll
                for (int j = 0; j < 8; ++j) { ag[j] += (float)ea0[j]; ag[8 + j] += (float)ea1[j]; }
            }
            if (d > 1) {
#pragma unroll
                for (int j = 0; j < 8; ++j) { ag[j] += (float)eb0[j]; ag[8 + j] += (float)eb1[j]; }
            }
            for (int j2 = p0 + 2; j2 < p1; j2 += 2) {   // paired tail (rare)
                { const bf16x8* q = (const bf16x8*)(fb + (size_t)sl32[2 * j2] * 256 + sl * 32); ea0 = q[0]; ea1 = q[1]; }
                const bool two = (j2 + 1 < p1);
                if (two) { const bf16x8* q = (const bf16x8*)(fb + (size_t)sl32[2 * (j2 + 1)] * 256 + sl * 32); eb0 = q[0]; eb1 = q[1]; }
#pragma unroll
                for (int j = 0; j < 8; ++j) { ag[j] += (float)ea0[j]; ag[8 + j] += (float)ea1[j]; }
                if (two) {
#pragma unroll
                    for (int j = 0; j < 8; ++j) { ag[j] += (float)eb0[j]; ag[8 + j] += (float)eb1[j]; }
                }
            }
            p0 = np0; p1 = np1; s0 = u0; s1 = u1; np0 = q0; np1 = q1;
#pragma unroll
            for (int j = 0; j < 8; ++j) { av0[j] = (bf16)ag[j]; av1[j] = (bf16)ag[8 + j]; }
        } else {
            // ctr self-term: A = own feat row (exact, no re-rounding)
            if (rowok) { const bf16x8* q = (const bf16x8*)(fb + (size_t)grow * 256 + sl * 32); av0 = q[0]; av1 = q[1]; }
            else { bf16x8 z{}; av0 = z; av1 = z; }
        }

        char* atb = (char*)AT[t & 1];
        *(bf16x8*)(atb + wb0) = av0;
        *(bf16x8*)(atb + wb1) = av1;
        __syncthreads();

        const char* atr = (const char*)AT[t & 1];
#pragma unroll
        for (int m = 0; m < 4; ++m) {
            const int arow = m * 16 + r;
#pragma unroll
            for (int kk = 0; kk < 4; ++kk) {
                const bf16x8 a = *(const bf16x8*)(atr + arow * 256 + (((kk * 4 + h) ^ r7) * 16));
                acc[m] = __builtin_amdgcn_mfma_f32_16x16x32_bf16(a, bfr[kk], acc[m], 0, 0, 0);
            }
        }
    }

    // ---- GN 1: cross-wave reduction (rows split across waves) ----
#pragma unroll
    for (int m = 0; m < 4; ++m) {
        float a1[4], a2[4];
#pragma unroll
        for (int g2 = 0; g2 < 4; ++g2) { const float v = acc[m][g2]; a1[g2] = v; a2[g2] = v * v; }
#pragma unroll
        for (int off = 1; off < 16; off <<= 1)
#pragma unroll
            for (int g2 = 0; g2 < 4; ++g2) {
                a1[g2] += __shfl_xor(a1[g2], off, 64);
                a2[g2] += __shfl_xor(a2[g2], off, 64);
            }
        if (r == 0) {
#pragma unroll
            for (int g2 = 0; g2 < 4; ++g2) {
                const int row = m * 16 + h * 4 + g2;
                red[(w * 64 + row) * 2]     = a1[g2];
                red[(w * 64 + row) * 2 + 1] = a2[g2];
            }
        }
    }
    __syncthreads();
    if (tid < 64) {
        float s1 = 0.f, s2 = 0.f;
#pragma unroll
        for (int ww = 0; ww < 8; ++ww) { s1 += red[(ww * 64 + tid) * 2]; s2 += red[(ww * 64 + tid) * 2 + 1]; }
        const float mn = s1 * 0.0078125f;
        const float vr = fmaxf(s2 * 0.0078125f - mn * mn, 0.f);
        stats[tid * 2]     = mn;
        stats[tid * 2 + 1] = rsqrtf(vr + 1e-5f);
    }
    __syncthreads();

    // epilogue 1: y = relu(gn(acc)) -> AT[0] (swizzled bf16 A-tile); load ctr2 B
    const float gv1 = ng[n0 + r], bv1 = nbg[n0 + r];
    bf16x8 bfr2[4];
#pragma unroll
    for (int kk = 0; kk < 4; ++kk)
        bfr2[kk] = *(const bf16x8*)(wCtr2R + (n0 + r) * 128 + kk * 32 + h * 8);
    {
        char* atb = (char*)AT[0];
        const int colb = (n0 + r) * 2;
#pragma unroll
        for (int m = 0; m < 4; ++m)
#pragma unroll
            for (int g2 = 0; g2 < 4; ++g2) {
                const int row = m * 16 + h * 4 + g2;
                const float y = (acc[m][g2] - stats[row * 2]) * stats[row * 2 + 1] * gv1 + bv1;
                const int slot = (colb >> 4) ^ (row & 7);
                *(bf16*)(atb + row * 256 + slot * 16 + (colb & 15)) = (bf16)fmaxf(y, 0.f);
            }
    }
    __syncthreads();

    // ctr2 GEMM
    f32x4 ac2[4];
    { f32x4 z = {0.f, 0.f, 0.f, 0.f}; ac2[0] = z; ac2[1] = z; ac2[2] = z; ac2[3] = z; }
    {
        const char* atr = (const char*)AT[0];
#pragma unroll
        for (int m = 0; m < 4; ++m) {
            const int arow = m * 16 + r;
#pragma unroll
            for (int kk = 0; kk < 4; ++kk) {
                const bf16x8 a = *(const bf16x8*)(atr + arow * 256 + (((kk * 4 + h) ^ r7) * 16));
                ac2[m] = __builtin_amdgcn_mfma_f32_16x16x32_bf16(a, bfr2[kk], ac2[m], 0, 0, 0);
            }
        }
    }

    // ---- GN 2 ----
#pragma unroll
    for (int m = 0; m < 4; ++m) {
        float a1[4], a2[4];
#pragma unroll
        for (int g2 = 0; g2 < 4; ++g2) { const float v = ac2[m][g2]; a1[g2] = v; a2[g2] = v * v; }
#pragma unroll
        for (int off = 1; off < 16; off <<= 1)
#pragma unroll
            for (int g2 = 0; g2 < 4; ++g2) {
                a1[g2] += __shfl_xor(a1[g2], off, 64);
                a2[g2] += __shfl_xor(a2[g2], off, 64);
            }
        if (r == 0) {
#pragma unroll
            for (int g2 = 0; g2 < 4; ++g2) {
                const int row = m * 16 + h * 4 + g2;
                red[(w * 64 + row) * 2]     = a1[g2];
                red[(w * 64 + row) * 2 + 1] = a2[g2];
            }
        }
    }
    __syncthreads();
    if (tid < 64) {
        float s1 = 0.f, s2 = 0.f;
#pragma unroll
        for (int ww = 0; ww < 8; ++ww) { s1 += red[(ww * 64 + tid) * 2]; s2 += red[(ww * 64 + tid) * 2 + 1]; }
        const float mn = s1 * 0.0078125f;
        const float vr = fmaxf(s2 * 0.0078125f - mn * mn, 0.f);
        stats[tid * 2]     = mn;
        stats[tid * 2 + 1] = rsqrtf(vr + 1e-5f);
    }
    __syncthreads();

    // epilogue 2: o = relu(gn(ac2) + feat)  -> featOut (bf16) or d_out (f32)
    const float gv2 = c2g[n0 + r], bv2 = c2bg[n0 + r];
#pragma unroll
    for (int m = 0; m < 4; ++m)
#pragma unroll
        for (int g2 = 0; g2 < 4; ++g2) {
            const int row = m * 16 + h * 4 + g2;
            const int orow = row0 + row;
            if (orow < NN) {
                const size_t off = (size_t)orow * 128 + n0 + r;
                const float y = (ac2[m][g2] - stats[row * 2]) * stats[row * 2 + 1] * gv2 + bv2;
                const float o = fmaxf(y + (float)feat[off], 0.f);
                if (last) outF[off] = o;
                else      featOut[off] = (bf16)o;
            }
        }
}

// ---------- launch ----------

extern "C" void kernel_launch(void* const* d_in, const int* in_sizes, int n_in,
                              void* d_out, int out_size, void* d_ws, size_t ws_size,
                              hipStream_t stream) {
    const float* nodes  = (const float*)d_in[0];
    const int*   idx    = (const int*)d_in[1];
    const int*   mask   = (const int*)d_in[2];
    const float* in1W   = (const float*)d_in[3];
    const float* in1b   = (const float*)d_in[4];
    const float* in2W   = (const float*)d_in[5];
    const float* ing    = (const float*)d_in[6];
    const float* inbg   = (const float*)d_in[7];
    const float* seg1W  = (const float*)d_in[8];
    const float* seg1b  = (const float*)d_in[9];
    const float* seg2W  = (const float*)d_in[10];
    const float* segg   = (const float*)d_in[11];
    const float* segbg  = (const float*)d_in[12];
    const float* metaW  = (const float*)d_in[13];
    const float* metag  = (const float*)d_in[14];
    const float* metabg = (const float*)d_in[15];
    const float* ctrW   = (const float*)d_in[16];
    const float* edgeW  = (const float*)d_in[17];
    const float* normg  = (const float*)d_in[18];
    const float* normbg = (const float*)d_in[19];
    const float* ctr2W  = (const float*)d_in[20];
    const float* ctr2g  = (const float*)d_in[21];
    const float* ctr2bg = (const float*)d_in[22];
    float* out = (float*)d_out;

    char* w = (char*)d_ws;
    bf16*  featB0 = (bf16*)w;  w += (size_t)NN * 128 * 2;
    bf16*  featB1 = (bf16*)w;  w += (size_t)NN * 128 * 2;
    bf16*  preB   = (bf16*)w;  w += (size_t)NN * 128 * 2;
    bf16*  wIn2   = (bf16*)w;  w += 16384 * 2;
    bf16*  wSeg2  = (bf16*)w;  w += 16384 * 2;
    bf16*  wMeta  = (bf16*)w;  w += 20480 * 2;
    bf16*  wCtr   = (bf16*)w;  w += 65536 * 2;
    bf16*  wCtr2  = (bf16*)w;  w += 65536 * 2;
    bf16*  wEdge  = (bf16*)w;  w += (size_t)917504 * 2;
    int*   cnt    = (int*)w;   w += (size_t)NCNT * 4;
    int*   ptr    = (int*)w;   w += ((size_t)NCNT + 4) * 4;
    int*   cursor = (int*)w;   w += (size_t)NCNT * 4;
    u64*   elist  = (u64*)w;   w += (size_t)14 * NE * 8 + 64;
    int*   tot    = (int*)w;   w += (NSCB + 1) * 4;

    dim3 blk(256);
    const int gRows = (NN + 63) / 64;

    // CSR build
    hipMemsetAsync(cnt, 0, (size_t)NCNT * 4, stream);
    k_count<<<2048, blk, 0, stream>>>(idx, mask, cnt);
    k_scanA<<<NSCB, blk, 0, stream>>>(cnt, ptr, tot);
    k_scanB<<<1, 64, 0, stream>>>(tot);
    k_scanC<<<NSCB, blk, 0, stream>>>(ptr, cursor, tot);
    k_fill<<<2048, blk, 0, stream>>>(idx, mask, cursor, elist);
    k_sortseg<<<2048, blk, 0, stream>>>(ptr, elist);

    // weights -> bf16 (+ nodes slice of the output)
    k_cvt_all<<<1024, blk, 0, stream>>>(in2W, seg2W, metaW, ctrW, ctr2W, edgeW,
                                        wIn2, wSeg2, wMeta, wCtr, wCtr2, wEdge,
                                        nodes, out);

    // encoders
    k_in<<<gRows, blk, 0, stream>>>(nodes, in1W, in1b, wIn2, ing, inbg,
                                    seg1W, seg1b, wSeg2, segg, segbg, preB);
    k_meta<<<gRows, blk, 0, stream>>>(preB, nodes, wMeta, metag, metabg, featB0);

    // 4 rounds; last round writes d_out directly
    bf16* bufs[2] = { featB0, featB1 };
    for (int i = 0; i < 4; ++i) {
        k_round<<<gRows, dim3(512), 0, stream>>>(bufs[i & 1], ptr, (const int*)elist,
                                                 wEdge + (size_t)i * 14 * 16384,
                                                 wCtr + (size_t)i * 16384,
                                                 wCtr2 + (size_t)i * 16384,
                                                 normg + i * 128, normbg + i * 128,
                                                 ctr2g + i * 128, ctr2bg + i * 128,
                                                 bufs[(i + 1) & 1], out,
                                                 i == 3 ? 1 : 0);
    }
}

// Round 9
// 1232.509 us; speedup vs baseline: 1.7340x; 1.1125x over previous
//
#include <hip/hip_runtime.h>
#include <hip/hip_bf16.h>

#define NN 100000
#define NE 100000
#define NCNT (14 * NN)
#define LP 136    // padded LDS pitch (bf16) for encoder kernels
#define LP2 168   // pitch for K=160 (meta)
#define SCAN_CHUNK 4096
#define NSCB ((NCNT + SCAN_CHUNK - 1) / SCAN_CHUNK)

typedef __bf16 bf16;
typedef __bf16 bf16x8 __attribute__((ext_vector_type(8)));
typedef float  f32x4  __attribute__((ext_vector_type(4)));
typedef unsigned long long u64;

// ---------- generic helpers ----------

__device__ __forceinline__ void zacc8(f32x4 acc[8]) {
    f32x4 z = {0.f, 0.f, 0.f, 0.f};
#pragma unroll
    for (int n = 0; n < 8; ++n) acc[n] = z;
}

// per-wave GroupNorm(1) stats (encoder kernels): wave holds 16 full rows
__device__ __forceinline__ void gnstats(const f32x4 acc[8], float mean[4], float rs[4]) {
    float s1[4], s2[4];
#pragma unroll
    for (int r = 0; r < 4; ++r) { s1[r] = 0.f; s2[r] = 0.f; }
#pragma unroll
    for (int n = 0; n < 8; ++n)
#pragma unroll
        for (int r = 0; r < 4; ++r) { float v = acc[n][r]; s1[r] += v; s2[r] += v * v; }
#pragma unroll
    for (int off = 1; off < 16; off <<= 1) {
#pragma unroll
        for (int r = 0; r < 4; ++r) {
            s1[r] += __shfl_xor(s1[r], off, 64);
            s2[r] += __shfl_xor(s2[r], off, 64);
        }
    }
#pragma unroll
    for (int r = 0; r < 4; ++r) {
        const float m = s1[r] * 0.0078125f;
        const float v = fmaxf(s2[r] * 0.0078125f - m * m, 0.f);
        mean[r] = m;
        rs[r] = rsqrtf(v + 1e-5f);
    }
}

// ---------- encoder-path helpers ----------

template<int PITCH, int COLS>
__device__ inline void stageWB(const bf16* __restrict__ Wg, bf16* Wl) {
    constexpr int NV = 128 * COLS / 8;
    for (int i = threadIdx.x; i < NV; i += 256) {
        const int e = i * 8;
        const int r = e / COLS, c = e % COLS;
        *(float4*)(&Wl[r * PITCH + c]) = ((const float4*)Wg)[i];
    }
}

template<int PITCH, int KSTEPS>
__device__ inline void mmaT(const bf16* Al, const bf16* Wl, int m0, int lane, f32x4 acc[8]) {
#pragma unroll
    for (int kk = 0; kk < KSTEPS; ++kk) {
        bf16x8 a = *(const bf16x8*)(&Al[(m0 + (lane & 15)) * PITCH + kk * 32 + (lane >> 4) * 8]);
#pragma unroll
        for (int n = 0; n < 8; ++n) {
            bf16x8 b = *(const bf16x8*)(&Wl[(n * 16 + (lane & 15)) * PITCH + kk * 32 + (lane >> 4) * 8]);
            acc[n] = __builtin_amdgcn_mfma_f32_16x16x32_bf16(a, b, acc[n], 0, 0, 0);
        }
    }
}

// ---------- weight conversion + nodes output slice (one kernel) ----------

__global__ __launch_bounds__(256) void k_cvt_all(
    const float* __restrict__ in2W, const float* __restrict__ seg2W,
    const float* __restrict__ metaW, const float* __restrict__ ctrW,
    const float* __restrict__ ctr2W, const float* __restrict__ edgeW,
    bf16* __restrict__ wIn2, bf16* __restrict__ wSeg2, bf16* __restrict__ wMeta,
    bf16* __restrict__ wCtr, bf16* __restrict__ wCtr2, bf16* __restrict__ wEdge,
    const float* __restrict__ nodes, float* __restrict__ outp)
{
    for (int j = blockIdx.x * 256 + threadIdx.x; j < 2 * NN; j += gridDim.x * 256)
        outp[(size_t)NN * 128 + j] = nodes[(size_t)(j >> 1) * 8 + (j & 1)];
    const int total = 16384 + 16384 + 20480 + 65536 + 65536 + 917504;
    for (int i = blockIdx.x * 256 + threadIdx.x; i < total; i += gridDim.x * 256) {
        int j = i;
        if (j < 16384) { wIn2[j] = (bf16)in2W[j]; continue; }
        j -= 16384;
        if (j < 16384) { wSeg2[j] = (bf16)seg2W[j]; continue; }
        j -= 16384;
        if (j < 20480) {
            const int r = j / 160, c = j % 160;
            wMeta[j] = (bf16)(c < 132 ? metaW[r * 132 + c] : 0.f);
            continue;
        }
        j -= 20480;
        if (j < 65536) { wCtr[j] = (bf16)ctrW[j]; continue; }
        j -= 65536;
        if (j < 65536) { wCtr2[j] = (bf16)ctr2W[j]; continue; }
        j -= 65536;
        wEdge[j] = (bf16)edgeW[j];
    }
}

// ---------- CSR build ----------

__global__ __launch_bounds__(256) void k_count(const int* __restrict__ idx,
                                               const int* __restrict__ mask,
                                               int* __restrict__ cnt) {
    __shared__ int lim[14];
    if (threadIdx.x < 14) lim[threadIdx.x] = min(mask[threadIdx.x], NE);
    __syncthreads();
    for (int i = blockIdx.x * 256 + threadIdx.x; i < 14 * NE; i += gridDim.x * 256) {
        const int e = i / 14, t = i - e * 14;
        if (e < lim[t]) atomicAdd(&cnt[t * NN + idx[(size_t)e * 28 + 2 * t]], 1);
    }
}

__global__ __launch_bounds__(256) void k_scanA(const int* __restrict__ cnt,
                                               int* __restrict__ ptr,
                                               int* __restrict__ tot) {
    __shared__ int sm[256];
    const int tid = threadIdx.x;
    const int base = blockIdx.x * SCAN_CHUNK + tid * 16;
    int v[16]; int run = 0;
#pragma unroll
    for (int j = 0; j < 16; ++j) {
        const int x = (base + j < NCNT) ? cnt[base + j] : 0;
        v[j] = run; run += x;
    }
    sm[tid] = run; __syncthreads();
    for (int d = 1; d < 256; d <<= 1) {
        int t = 0;
        if (tid >= d) t = sm[tid - d];
        __syncthreads();
        sm[tid] += t;
        __syncthreads();
    }
    const int off = sm[tid] - run;
#pragma unroll
    for (int j = 0; j < 16; ++j)
        if (base + j < NCNT) ptr[base + j] = v[j] + off;
    if (tid == 255) tot[blockIdx.x] = sm[255];
}

__global__ void k_scanB(int* __restrict__ tot) {
    if (threadIdx.x == 0 && blockIdx.x == 0) {
        int acc = 0;
        for (int b = 0; b < NSCB; ++b) { const int t = tot[b]; tot[b] = acc; acc += t; }
        tot[NSCB] = acc;
    }
}

__global__ __launch_bounds__(256) void k_scanC(int* __restrict__ ptr,
                                               int* __restrict__ cursor,
                                               const int* __restrict__ tot) {
    const int base = blockIdx.x * SCAN_CHUNK;
    const int o = tot[blockIdx.x];
    for (int j = threadIdx.x; j < SCAN_CHUNK; j += 256) {
        const int i = base + j;
        if (i < NCNT) { const int p = ptr[i] + o; ptr[i] = p; cursor[i] = p; }
    }
    if (blockIdx.x == 0 && threadIdx.x == 0) ptr[NCNT] = tot[NSCB];
}

// elist entry: (edge_id << 32) | src
__global__ __launch_bounds__(256) void k_fill(const int* __restrict__ idx,
                                              const int* __restrict__ mask,
                                              int* __restrict__ cursor,
                                              u64* __restrict__ el) {
    __shared__ int lim[14];
    if (threadIdx.x < 14) lim[threadIdx.x] = min(mask[threadIdx.x], NE);
    __syncthreads();
    for (int i = blockIdx.x * 256 + threadIdx.x; i < 14 * NE; i += gridDim.x * 256) {
        const int e = i / 14, t = i - e * 14;
        if (e < lim[t]) {
            const int dst = idx[(size_t)e * 28 + 2 * t];
            const int src = idx[(size_t)e * 28 + 2 * t + 1];
            const int pos = atomicAdd(&cursor[t * NN + dst], 1);
            el[pos] = ((u64)(unsigned)e << 32) | (unsigned)src;
        }
    }
}

__global__ __launch_bounds__(256) void k_sortseg(const int* __restrict__ ptr,
                                                 u64* __restrict__ el) {
    for (int i = blockIdx.x * 256 + threadIdx.x; i < NCNT; i += gridDim.x * 256) {
        const int s = ptr[i], e2 = ptr[i + 1];
        for (int a = s + 1; a < e2; ++a) {
            const u64 key = el[a];
            int b = a - 1;
            while (b >= s && el[b] > key) { el[b + 1] = el[b]; --b; }
            el[b + 1] = key;
        }
    }
}

// ---------- input encoder ----------

__global__ __launch_bounds__(256) void k_in(
    const float* __restrict__ nodes,
    const float* __restrict__ in1W, const float* __restrict__ in1b,
    const bf16* __restrict__ wIn2,
    const float* __restrict__ ing, const float* __restrict__ inbg,
    const float* __restrict__ seg1W, const float* __restrict__ seg1b,
    const bf16* __restrict__ wSeg2,
    const float* __restrict__ segg, const float* __restrict__ segbg,
    bf16* __restrict__ outPre)
{
    __shared__ __align__(16) bf16 Wl[128 * LP];
    __shared__ __align__(16) bf16 Al[64 * LP];
    __shared__ float w0[128], w1[128], bb[128];
    __shared__ float xs[64][4];
    const int tid = threadIdx.x;
    const int row0 = blockIdx.x * 64;
    if (tid < 64) {
        const int row = row0 + tid;
        float4 x = {0.f, 0.f, 0.f, 0.f};
        if (row < NN) x = *(const float4*)(nodes + (size_t)row * 8);
        xs[tid][0] = x.x; xs[tid][1] = x.y; xs[tid][2] = x.z; xs[tid][3] = x.w;
    }
    if (tid < 128) { w0[tid] = in1W[tid * 2]; w1[tid] = in1W[tid * 2 + 1]; bb[tid] = in1b[tid]; }
    stageWB<LP, 128>(wIn2, Wl);
    __syncthreads();
    for (int i = tid; i < 64 * 128; i += 256) {
        const int r = i >> 7, j = i & 127;
        Al[r * LP + j] = (bf16)fmaxf(xs[r][0] * w0[j] + xs[r][1] * w1[j] + bb[j], 0.f);
    }
    __syncthreads();
    const int lane = tid & 63, m0 = (tid >> 6) * 16;
    f32x4 accP[8]; zacc8(accP);
    mmaT<LP, 4>(Al, Wl, m0, lane, accP);
    __syncthreads();
    if (tid < 128) { w0[tid] = seg1W[tid * 2]; w1[tid] = seg1W[tid * 2 + 1]; bb[tid] = seg1b[tid]; }
    stageWB<LP, 128>(wSeg2, Wl);
    __syncthreads();
    for (int i = tid; i < 64 * 128; i += 256) {
        const int r = i >> 7, j = i & 127;
        Al[r * LP + j] = (bf16)fmaxf(xs[r][2] * w0[j] + xs[r][3] * w1[j] + bb[j], 0.f);
    }
    __syncthreads();
    f32x4 accQ[8]; zacc8(accQ);
    mmaT<LP, 4>(Al, Wl, m0, lane, accQ);

    float mP[4], rP[4], mQ[4], rQ[4];
    gnstats(accP, mP, rP);
    gnstats(accQ, mQ, rQ);
    float gP[8], bP[8], gQ[8], bQ[8];
#pragma unroll
    for (int n = 0; n < 8; ++n) {
        const int c = n * 16 + (lane & 15);
        gP[n] = ing[c]; bP[n] = inbg[c]; gQ[n] = segg[c]; bQ[n] = segbg[c];
    }
#pragma unroll
    for (int r = 0; r < 4; ++r) {
        const int row = row0 + m0 + (lane >> 4) * 4 + r;
        if (row < NN) {
#pragma unroll
            for (int n = 0; n < 8; ++n) {
                const float yp = (accP[n][r] - mP[r]) * rP[r] * gP[n] + bP[n];
                const float yq = (accQ[n][r] - mQ[r]) * rQ[r] * gQ[n] + bQ[n];
                outPre[(size_t)row * 128 + n * 16 + (lane & 15)] = (bf16)fmaxf(yp + yq, 0.f);
            }
        }
    }
}

// ---------- meta ----------

__global__ __launch_bounds__(256) void k_meta(
    const bf16* __restrict__ Apre, const float* __restrict__ nodes,
    const bf16* __restrict__ Wg,
    const float* __restrict__ g, const float* __restrict__ bg,
    bf16* __restrict__ featB)
{
    __shared__ __align__(16) bf16 Wl[128 * LP2];
    __shared__ __align__(16) bf16 Al[64 * LP2];
    const int row0 = blockIdx.x * 64;
    stageWB<LP2, 160>(Wg, Wl);
    {
        const int r = threadIdx.x >> 2, q = threadIdx.x & 3;
        float4* d = (float4*)(&Al[r * LP2 + q * 32]);
        const int row = row0 + r;
        if (row < NN) {
            const float4* s = (const float4*)(Apre + (size_t)row * 128 + q * 32);
            float4 a0 = s[0], a1 = s[1], a2 = s[2], a3 = s[3];
            d[0] = a0; d[1] = a1; d[2] = a2; d[3] = a3;
        } else {
            float4 z = {0.f, 0.f, 0.f, 0.f};
            d[0] = z; d[1] = z; d[2] = z; d[3] = z;
        }
    }
    if (threadIdx.x < 64) {
        const int rr = threadIdx.x, row = row0 + rr;
        bf16* d = &Al[rr * LP2 + 128];
        if (row < NN) {
            const float4 x = *(const float4*)(nodes + (size_t)row * 8 + 4);
            d[0] = (bf16)x.x; d[1] = (bf16)x.y; d[2] = (bf16)x.z; d[3] = (bf16)x.w;
        } else {
            d[0] = (bf16)0.f; d[1] = (bf16)0.f; d[2] = (bf16)0.f; d[3] = (bf16)0.f;
        }
#pragma unroll
        for (int c = 4; c < 32; ++c) d[c] = (bf16)0.f;
    }
    __syncthreads();
    const int lane = threadIdx.x & 63, m0 = (threadIdx.x >> 6) * 16;
    f32x4 acc[8]; zacc8(acc);
    mmaT<LP2, 5>(Al, Wl, m0, lane, acc);

    float mean[4], rs[4];
    gnstats(acc, mean, rs);
    float gv[8], bv[8];
#pragma unroll
    for (int n = 0; n < 8; ++n) { const int c = n * 16 + (lane & 15); gv[n] = g[c]; bv[n] = bg[c]; }
#pragma unroll
    for (int r = 0; r < 4; ++r) {
        const int row = row0 + m0 + (lane >> 4) * 4 + r;
        if (row < NN) {
            const size_t off = (size_t)row * 128 + (lane & 15);
#pragma unroll
            for (int n = 0; n < 8; ++n) {
                const float y = (acc[n][r] - mean[r]) * rs[r] * gv[n] + bv[n];
                featB[off + n * 16] = (bf16)fmaxf(y, 0.f);
            }
        }
    }
}

// ---------- fused round, gather pipelined one phase ahead ----------
// M=64/block, 512 threads = 8 waves; wave w owns output cols w*16..w*16+15.
// ag (aggregate for type t) is computed during phase t-1 and written at the
// top of phase t. Raw s_barrier with lgkmcnt-only drain keeps global loads
// (W frags, index prefetch) in flight across barriers.

__global__ __launch_bounds__(512, 2) void k_round(
    const bf16* __restrict__ feat,
    const int* __restrict__ ptr,
    const int* __restrict__ sl32,      // u64 elist as int pairs; src = sl32[2*j]
    const bf16* __restrict__ wEdgeR,   // 14 * 16384
    const bf16* __restrict__ wCtrR,
    const bf16* __restrict__ wCtr2R,
    const float* __restrict__ ng, const float* __restrict__ nbg,
    const float* __restrict__ c2g, const float* __restrict__ c2bg,
    bf16* __restrict__ featOut,
    float* __restrict__ outF,
    int last)
{
    __shared__ __align__(16) bf16 AT[2][64 * 128];   // 2 x 16KB A tiles
    __shared__ float red[8 * 64 * 2];                // per-wave GN partials
    __shared__ float stats[64 * 2];                  // mean, rsqrt per row

    const int tid = threadIdx.x;
    const int w = tid >> 6, lane = tid & 63;
    const int r = lane & 15, h = lane >> 4, r7 = r & 7;
    const int n0 = w * 16;                 // wave's output column base
    const int row0 = blockIdx.x * 64;

    // gather role: 8 threads per row, 32B (16 bf16) slice each
    const int rr = tid >> 3, sl = tid & 7;
    const int grow = row0 + rr;
    const bool rowok = grow < NN;
    const int wb0 = rr * 256 + (((2 * sl)     ^ (rr & 7)) * 16);
    const int wb1 = rr * 256 + (((2 * sl + 1) ^ (rr & 7)) * 16);

    // CSR state: (p0,p1,s0,s1) = type to gather next; (np0,np1) = type after
    int p0 = 0, p1 = 0;
    if (rowok) { p0 = ptr[grow]; p1 = ptr[grow + 1]; }
    int s0 = 0, s1 = 0;
    if (p1 > p0)     s0 = sl32[2 * p0];
    if (p1 > p0 + 1) s1 = sl32[2 * (p0 + 1)];
    int np0 = 0, np1 = 0;
    if (rowok) { np0 = ptr[NN + grow]; np1 = ptr[NN + grow + 1]; }

    const char* fb = (const char*)feat;
    float ag[16];

    // ---- preloop: gather type 0 into ag (latency exposed once) ----
    {
        const int d = p1 - p0;
        bf16x8 ea0, ea1, eb0, eb1;
        if (d > 0) { const bf16x8* q = (const bf16x8*)(fb + (size_t)s0 * 256 + sl * 32); ea0 = q[0]; ea1 = q[1]; }
        if (d > 1) { const bf16x8* q = (const bf16x8*)(fb + (size_t)s1 * 256 + sl * 32); eb0 = q[0]; eb1 = q[1]; }
        int u0 = 0, u1 = 0;
        { const int dn = np1 - np0;
          if (dn > 0) u0 = sl32[2 * np0];
          if (dn > 1) u1 = sl32[2 * np0 + 2]; }
        int q0 = 0, q1 = 0;
        if (rowok) { const size_t b2 = (size_t)2 * NN + grow; q0 = ptr[b2]; q1 = ptr[b2 + 1]; }
#pragma unroll
        for (int j = 0; j < 16; ++j) ag[j] = 0.f;
        if (d > 0) {
#pragma unroll
            for (int j = 0; j < 8; ++j) { ag[j] += (float)ea0[j]; ag[8 + j] += (float)ea1[j]; }
        }
        if (d > 1) {
#pragma unroll
            for (int j = 0; j < 8; ++j) { ag[j] += (float)eb0[j]; ag[8 + j] += (float)eb1[j]; }
        }
        for (int j2 = p0 + 2; j2 < p1; j2 += 2) {
            { const bf16x8* q = (const bf16x8*)(fb + (size_t)sl32[2 * j2] * 256 + sl * 32); ea0 = q[0]; ea1 = q[1]; }
            const bool two = (j2 + 1 < p1);
            if (two) { const bf16x8* q = (const bf16x8*)(fb + (size_t)sl32[2 * (j2 + 1)] * 256 + sl * 32); eb0 = q[0]; eb1 = q[1]; }
#pragma unroll
            for (int j = 0; j < 8; ++j) { ag[j] += (float)ea0[j]; ag[8 + j] += (float)ea1[j]; }
            if (two) {
#pragma unroll
                for (int j = 0; j < 8; ++j) { ag[j] += (float)eb0[j]; ag[8 + j] += (float)eb1[j]; }
            }
        }
        p0 = np0; p1 = np1; s0 = u0; s1 = u1; np0 = q0; np1 = q1;
    }

    f32x4 acc[4];
    { f32x4 z = {0.f, 0.f, 0.f, 0.f}; acc[0] = z; acc[1] = z; acc[2] = z; acc[3] = z; }

    for (int t = 0; t < 15; ++t) {
        // write ag (aggregate for type t) into AT[t&1]
        {
            bf16x8 av0, av1;
#pragma unroll
            for (int j = 0; j < 8; ++j) { av0[j] = (bf16)ag[j]; av1[j] = (bf16)ag[8 + j]; }
            char* atb = (char*)AT[t & 1];
            *(bf16x8*)(atb + wb0) = av0;
            *(bf16x8*)(atb + wb1) = av1;
        }
        // B fragments for this phase (global; latency hidden by barrier wait)
        const bf16* Wt = (t < 14) ? (wEdgeR + (size_t)t * 16384) : wCtrR;
        bf16x8 bfr[4];
#pragma unroll
        for (int kk = 0; kk < 4; ++kk)
            bfr[kk] = *(const bf16x8*)(Wt + (n0 + r) * 128 + kk * 32 + h * 8);

        asm volatile("s_waitcnt lgkmcnt(0)" ::: "memory");  // LDS writes visible
        __builtin_amdgcn_s_barrier();                       // (global loads stay in flight)
        __builtin_amdgcn_sched_barrier(0);

        // issue next-phase gather head loads + index prefetch BEFORE MFMA
        const int tt = t + 1;
        bf16x8 ea0, ea1, eb0, eb1;
        int d = 0, u0 = 0, u1 = 0, q0 = 0, q1 = 0;
        if (tt < 14) {
            d = p1 - p0;
            if (d > 0) { const bf16x8* q = (const bf16x8*)(fb + (size_t)s0 * 256 + sl * 32); ea0 = q[0]; ea1 = q[1]; }
            if (d > 1) { const bf16x8* q = (const bf16x8*)(fb + (size_t)s1 * 256 + sl * 32); eb0 = q[0]; eb1 = q[1]; }
            if (tt <= 12) {
                const int dn = np1 - np0;
                if (dn > 0) u0 = sl32[2 * np0];
                if (dn > 1) u1 = sl32[2 * np0 + 2];
            }
            if (tt <= 11 && rowok) {
                const size_t b2 = (size_t)(tt + 2) * NN + grow;
                q0 = ptr[b2]; q1 = ptr[b2 + 1];
            }
        } else if (tt == 14) {
            // ctr self-term: own feat row (bf16->f32->bf16 roundtrip exact)
            if (rowok) { const bf16x8* q = (const bf16x8*)(fb + (size_t)grow * 256 + sl * 32); ea0 = q[0]; ea1 = q[1]; d = 1; }
        }

        // MFMA[t] from AT[t&1]
        {
            const char* atr = (const char*)AT[t & 1];
#pragma unroll
            for (int m = 0; m < 4; ++m) {
                const int arow = m * 16 + r;
#pragma unroll
                for (int kk = 0; kk < 4; ++kk) {
                    const bf16x8 a = *(const bf16x8*)(atr + arow * 256 + (((kk * 4 + h) ^ r7) * 16));
                    acc[m] = __builtin_amdgcn_mfma_f32_16x16x32_bf16(a, bfr[kk], acc[m], 0, 0, 0);
                }
            }
        }

        // finish gather for tt (accumulate heads + rare serial tail)
        if (tt <= 14) {
#pragma unroll
            for (int j = 0; j < 16; ++j) ag[j] = 0.f;
            if (d > 0) {
#pragma unroll
                for (int j = 0; j < 8; ++j) { ag[j] += (float)ea0[j]; ag[8 + j] += (float)ea1[j]; }
            }
            if (tt < 14) {
                if (d > 1) {
#pragma unroll
                    for (int j = 0; j < 8; ++j) { ag[j] += (float)eb0[j]; ag[8 + j] += (float)eb1[j]; }
                }
                for (int j2 = p0 + 2; j2 < p1; j2 += 2) {
                    { const bf16x8* q = (const bf16x8*)(fb + (size_t)sl32[2 * j2] * 256 + sl * 32); ea0 = q[0]; ea1 = q[1]; }
                    const bool two = (j2 + 1 < p1);
                    if (two) { const bf16x8* q = (const bf16x8*)(fb + (size_t)sl32[2 * (j2 + 1)] * 256 + sl * 32); eb0 = q[0]; eb1 = q[1]; }
#pragma unroll
                    for (int j = 0; j < 8; ++j) { ag[j] += (float)ea0[j]; ag[8 + j] += (float)ea1[j]; }
                    if (two) {
#pragma unroll
                        for (int j = 0; j < 8; ++j) { ag[j] += (float)eb0[j]; ag[8 + j] += (float)eb1[j]; }
                    }
                }
                p0 = np0; p1 = np1; s0 = u0; s1 = u1; np0 = q0; np1 = q1;
            }
        }
    }

    // ---- GN 1: cross-wave reduction (rows split across waves) ----
#pragma unroll
    for (int m = 0; m < 4; ++m) {
        float a1[4], a2[4];
#pragma unroll
        for (int g2 = 0; g2 < 4; ++g2) { const float v = acc[m][g2]; a1[g2] = v; a2[g2] = v * v; }
#pragma unroll
        for (int off = 1; off < 16; off <<= 1)
#pragma unroll
            for (int g2 = 0; g2 < 4; ++g2) {
                a1[g2] += __shfl_xor(a1[g2], off, 64);
                a2[g2] += __shfl_xor(a2[g2], off, 64);
            }
        if (r == 0) {
#pragma unroll
            for (int g2 = 0; g2 < 4; ++g2) {
                const int row = m * 16 + h * 4 + g2;
                red[(w * 64 + row) * 2]     = a1[g2];
                red[(w * 64 + row) * 2 + 1] = a2[g2];
            }
        }
    }
    __syncthreads();
    if (tid < 64) {
        float s1 = 0.f, s2 = 0.f;
#pragma unroll
        for (int ww = 0; ww < 8; ++ww) { s1 += red[(ww * 64 + tid) * 2]; s2 += red[(ww * 64 + tid) * 2 + 1]; }
        const float mn = s1 * 0.0078125f;
        const float vr = fmaxf(s2 * 0.0078125f - mn * mn, 0.f);
        stats[tid * 2]     = mn;
        stats[tid * 2 + 1] = rsqrtf(vr + 1e-5f);
    }
    __syncthreads();

    // epilogue 1: y = relu(gn(acc)) -> AT[0] (swizzled bf16 A-tile); load ctr2 B
    const float gv1 = ng[n0 + r], bv1 = nbg[n0 + r];
    bf16x8 bfr2[4];
#pragma unroll
    for (int kk = 0; kk < 4; ++kk)
        bfr2[kk] = *(const bf16x8*)(wCtr2R + (n0 + r) * 128 + kk * 32 + h * 8);
    {
        char* atb = (char*)AT[0];
        const int colb = (n0 + r) * 2;
#pragma unroll
        for (int m = 0; m < 4; ++m)
#pragma unroll
            for (int g2 = 0; g2 < 4; ++g2) {
                const int row = m * 16 + h * 4 + g2;
                const float y = (acc[m][g2] - stats[row * 2]) * stats[row * 2 + 1] * gv1 + bv1;
                const int slot = (colb >> 4) ^ (row & 7);
                *(bf16*)(atb + row * 256 + slot * 16 + (colb & 15)) = (bf16)fmaxf(y, 0.f);
            }
    }
    __syncthreads();

    // ctr2 GEMM
    f32x4 ac2[4];
    { f32x4 z = {0.f, 0.f, 0.f, 0.f}; ac2[0] = z; ac2[1] = z; ac2[2] = z; ac2[3] = z; }
    {
        const char* atr = (const char*)AT[0];
#pragma unroll
        for (int m = 0; m < 4; ++m) {
            const int arow = m * 16 + r;
#pragma unroll
            for (int kk = 0; kk < 4; ++kk) {
                const bf16x8 a = *(const bf16x8*)(atr + arow * 256 + (((kk * 4 + h) ^ r7) * 16));
                ac2[m] = __builtin_amdgcn_mfma_f32_16x16x32_bf16(a, bfr2[kk], ac2[m], 0, 0, 0);
            }
        }
    }

    // ---- GN 2 ----
#pragma unroll
    for (int m = 0; m < 4; ++m) {
        float a1[4], a2[4];
#pragma unroll
        for (int g2 = 0; g2 < 4; ++g2) { const float v = ac2[m][g2]; a1[g2] = v; a2[g2] = v * v; }
#pragma unroll
        for (int off = 1; off < 16; off <<= 1)
#pragma unroll
            for (int g2 = 0; g2 < 4; ++g2) {
                a1[g2] += __shfl_xor(a1[g2], off, 64);
                a2[g2] += __shfl_xor(a2[g2], off, 64);
            }
        if (r == 0) {
#pragma unroll
            for (int g2 = 0; g2 < 4; ++g2) {
                const int row = m * 16 + h * 4 + g2;
                red[(w * 64 + row) * 2]     = a1[g2];
                red[(w * 64 + row) * 2 + 1] = a2[g2];
            }
        }
    }
    __syncthreads();
    if (tid < 64) {
        float s1 = 0.f, s2 = 0.f;
#pragma unroll
        for (int ww = 0; ww < 8; ++ww) { s1 += red[(ww * 64 + tid) * 2]; s2 += red[(ww * 64 + tid) * 2 + 1]; }
        const float mn = s1 * 0.0078125f;
        const float vr = fmaxf(s2 * 0.0078125f - mn * mn, 0.f);
        stats[tid * 2]     = mn;
        stats[tid * 2 + 1] = rsqrtf(vr + 1e-5f);
    }
    __syncthreads();

    // epilogue 2: o = relu(gn(ac2) + feat)  -> featOut (bf16) or d_out (f32)
    const float gv2 = c2g[n0 + r], bv2 = c2bg[n0 + r];
#pragma unroll
    for (int m = 0; m < 4; ++m)
#pragma unroll
        for (int g2 = 0; g2 < 4; ++g2) {
            const int row = m * 16 + h * 4 + g2;
            const int orow = row0 + row;
            if (orow < NN) {
                const size_t off = (size_t)orow * 128 + n0 + r;
                const float y = (ac2[m][g2] - stats[row * 2]) * stats[row * 2 + 1] * gv2 + bv2;
                const float o = fmaxf(y + (float)feat[off], 0.f);
                if (last) outF[off] = o;
                else      featOut[off] = (bf16)o;
            }
        }
}

// ---------- launch ----------

extern "C" void kernel_launch(void* const* d_in, const int* in_sizes, int n_in,
                              void* d_out, int out_size, void* d_ws, size_t ws_size,
                              hipStream_t stream) {
    const float* nodes  = (const float*)d_in[0];
    const int*   idx    = (const int*)d_in[1];
    const int*   mask   = (const int*)d_in[2];
    const float* in1W   = (const float*)d_in[3];
    const float* in1b   = (const float*)d_in[4];
    const float* in2W   = (const float*)d_in[5];
    const float* ing    = (const float*)d_in[6];
    const float* inbg   = (const float*)d_in[7];
    const float* seg1W  = (const float*)d_in[8];
    const float* seg1b  = (const float*)d_in[9];
    const float* seg2W  = (const float*)d_in[10];
    const float* segg   = (const float*)d_in[11];
    const float* segbg  = (const float*)d_in[12];
    const float* metaW  = (const float*)d_in[13];
    const float* metag  = (const float*)d_in[14];
    const float* metabg = (const float*)d_in[15];
    const float* ctrW   = (const float*)d_in[16];
    const float* edgeW  = (const float*)d_in[17];
    const float* normg  = (const float*)d_in[18];
    const float* normbg = (const float*)d_in[19];
    const float* ctr2W  = (const float*)d_in[20];
    const float* ctr2g  = (const float*)d_in[21];
    const float* ctr2bg = (const float*)d_in[22];
    float* out = (float*)d_out;

    char* w = (char*)d_ws;
    bf16*  featB0 = (bf16*)w;  w += (size_t)NN * 128 * 2;
    bf16*  featB1 = (bf16*)w;  w += (size_t)NN * 128 * 2;
    bf16*  preB   = (bf16*)w;  w += (size_t)NN * 128 * 2;
    bf16*  wIn2   = (bf16*)w;  w += 16384 * 2;
    bf16*  wSeg2  = (bf16*)w;  w += 16384 * 2;
    bf16*  wMeta  = (bf16*)w;  w += 20480 * 2;
    bf16*  wCtr   = (bf16*)w;  w += 65536 * 2;
    bf16*  wCtr2  = (bf16*)w;  w += 65536 * 2;
    bf16*  wEdge  = (bf16*)w;  w += (size_t)917504 * 2;
    int*   cnt    = (int*)w;   w += (size_t)NCNT * 4;
    int*   ptr    = (int*)w;   w += ((size_t)NCNT + 4) * 4;
    int*   cursor = (int*)w;   w += (size_t)NCNT * 4;
    u64*   elist  = (u64*)w;   w += (size_t)14 * NE * 8 + 64;
    int*   tot    = (int*)w;   w += (NSCB + 1) * 4;

    dim3 blk(256);
    const int gRows = (NN + 63) / 64;

    // CSR build
    hipMemsetAsync(cnt, 0, (size_t)NCNT * 4, stream);
    k_count<<<2048, blk, 0, stream>>>(idx, mask, cnt);
    k_scanA<<<NSCB, blk, 0, stream>>>(cnt, ptr, tot);
    k_scanB<<<1, 64, 0, stream>>>(tot);
    k_scanC<<<NSCB, blk, 0, stream>>>(ptr, cursor, tot);
    k_fill<<<2048, blk, 0, stream>>>(idx, mask, cursor, elist);
    k_sortseg<<<2048, blk, 0, stream>>>(ptr, elist);

    // weights -> bf16 (+ nodes slice of the output)
    k_cvt_all<<<1024, blk, 0, stream>>>(in2W, seg2W, metaW, ctrW, ctr2W, edgeW,
                                        wIn2, wSeg2, wMeta, wCtr, wCtr2, wEdge,
                                        nodes, out);

    // encoders
    k_in<<<gRows, blk, 0, stream>>>(nodes, in1W, in1b, wIn2, ing, inbg,
                                    seg1W, seg1b, wSeg2, segg, segbg, preB);
    k_meta<<<gRows, blk, 0, stream>>>(preB, nodes, wMeta, metag, metabg, featB0);

    // 4 rounds; last round writes d_out directly
    bf16* bufs[2] = { featB0, featB1 };
    for (int i = 0; i < 4; ++i) {
        k_round<<<gRows, dim3(512), 0, stream>>>(bufs[i & 1], ptr, (const int*)elist,
                                                 wEdge + (size_t)i * 14 * 16384,
                                                 wCtr + (size_t)i * 16384,
                                                 wCtr2 + (size_t)i * 16384,
                                                 normg + i * 128, normbg + i * 128,
                                                 ctr2g + i * 128, ctr2bg + i * 128,
                                                 bufs[(i + 1) & 1], out,
                                                 i == 3 ? 1 : 0);
    }
}